// Round 2
// baseline (12981.764 us; speedup 1.0000x reference)
//
#include <hip/hip_runtime.h>
#include <hip/hip_bf16.h>

typedef __attribute__((ext_vector_type(8))) short s16x8;
typedef __attribute__((ext_vector_type(4))) float f32x4;

__device__ inline unsigned short f2bf(float f) {
  unsigned u = __builtin_bit_cast(unsigned, f);
  unsigned r = (u + 0x7FFFu + ((u >> 16) & 1u)) >> 16;  // RTNE
  return (unsigned short)r;
}
__device__ inline float bf2f(short v) {
  return __builtin_bit_cast(float, ((unsigned)(unsigned short)v) << 16);
}
__device__ inline float sigf(float x) { return 1.f / (1.f + __expf(-x)); }
__device__ inline float tanhf_(float x) { float e = __expf(2.f * x); return 1.f - 2.f / (e + 1.f); }

// ---------------------------------------------------------------- conv/pad
__global__ void conv_pad(const float* __restrict__ src, unsigned short* __restrict__ dst,
                         int rows, int scols, int dcols) {
  int i = blockIdx.x * 256 + threadIdx.x;
  if (i >= rows * dcols) return;
  int r = i / dcols, cc = i % dcols;
  dst[i] = (cc < scols) ? f2bf(src[(size_t)r * scols + cc]) : (unsigned short)0;
}

// ---------------------------------------------------------------- GEMM C = A @ B^T + bias
// A: [M,K] (f32 or bf16), B: [N,K] f32 (weights), C: [M,N] (f32 or bf16)
#define BM 128
#define BN 128
#define BKK 32

template<int A_BF16, int C_BF16>
__global__ __launch_bounds__(256) void gemm_bt(const void* __restrict__ Av,
    const float* __restrict__ B, const float* __restrict__ bias,
    void* __restrict__ Cv, int M, int N, int K) {
  __shared__ short sA[BM * BKK];
  __shared__ short sB[BN * BKK];
  const int tid = threadIdx.x;
  const int l = tid & 63;
  const int wid = tid >> 6;
  const int wr = wid >> 1, wc = wid & 1;
  const int lr = l & 15, kg = l >> 4;
  const int bn = blockIdx.x, bm = blockIdx.y;   // bn fastest -> A-tile L2 reuse
  const int arow = tid >> 1;
  const int acol = (tid & 1) * 16;

  f32x4 acc[4][4];
#pragma unroll
  for (int i = 0; i < 4; ++i)
#pragma unroll
    for (int j = 0; j < 4; ++j) acc[i][j] = (f32x4){0.f, 0.f, 0.f, 0.f};

  for (int kt = 0; kt < K; kt += BKK) {
    __syncthreads();
    if (A_BF16) {
      const unsigned short* src = (const unsigned short*)Av + (size_t)(bm * BM + arow) * K + kt + acol;
      *(s16x8*)&sA[arow * BKK + acol] = *(const s16x8*)src;
      *(s16x8*)&sA[arow * BKK + acol + 8] = *(const s16x8*)(src + 8);
    } else {
      const float* src = (const float*)Av + (size_t)(bm * BM + arow) * K + kt + acol;
      s16x8 v0, v1;
#pragma unroll
      for (int e = 0; e < 8; ++e) { v0[e] = (short)f2bf(src[e]); v1[e] = (short)f2bf(src[8 + e]); }
      *(s16x8*)&sA[arow * BKK + acol] = v0;
      *(s16x8*)&sA[arow * BKK + acol + 8] = v1;
    }
    {
      const float* src = B + (size_t)(bn * BN + arow) * K + kt + acol;
      s16x8 v0, v1;
#pragma unroll
      for (int e = 0; e < 8; ++e) { v0[e] = (short)f2bf(src[e]); v1[e] = (short)f2bf(src[8 + e]); }
      *(s16x8*)&sB[arow * BKK + acol] = v0;
      *(s16x8*)&sB[arow * BKK + acol + 8] = v1;
    }
    __syncthreads();
    s16x8 af[4], bfr[4];
#pragma unroll
    for (int mi = 0; mi < 4; ++mi)
      af[mi] = *(const s16x8*)&sA[(wr * 64 + mi * 16 + lr) * BKK + kg * 8];
#pragma unroll
    for (int ni = 0; ni < 4; ++ni)
      bfr[ni] = *(const s16x8*)&sB[(wc * 64 + ni * 16 + lr) * BKK + kg * 8];
#pragma unroll
    for (int mi = 0; mi < 4; ++mi)
#pragma unroll
      for (int ni = 0; ni < 4; ++ni)
        acc[mi][ni] = __builtin_amdgcn_mfma_f32_16x16x32_bf16(af[mi], bfr[ni], acc[mi][ni], 0, 0, 0);
  }
  const int r0 = bm * BM + wr * 64;
  const int c0 = bn * BN + wc * 64;
#pragma unroll
  for (int mi = 0; mi < 4; ++mi)
#pragma unroll
    for (int ni = 0; ni < 4; ++ni) {
      const int col = c0 + ni * 16 + lr;
      const float bv = bias[col];
#pragma unroll
      for (int e = 0; e < 4; ++e) {
        const int row = r0 + mi * 16 + kg * 4 + e;
        const float v = acc[mi][ni][e] + bv;
        if (C_BF16) ((unsigned short*)Cv)[(size_t)row * N + col] = f2bf(v);
        else        ((float*)Cv)[(size_t)row * N + col] = v;
      }
    }
}

// ---------------------------------------------------------------- LSTM scan (one layer)
// pre: [T][128][512] f32 (x@Wih.T + b precomputed), Whh: [512][128] f32, hs out: [T][128][128] bf16.
// 8 WGs x 512 threads; WG owns 16 batch rows for the whole scan. Whh fragments hoisted to VGPRs.
__global__ __launch_bounds__(512) void lstm_scan(const float* __restrict__ pre,
    const float* __restrict__ Whh, unsigned short* __restrict__ hs, int T) {
  __shared__ unsigned short hb[2][2048];   // double-buffered h tile [16][128] bf16, XOR-swizzled
  const int tid = threadIdx.x;
  const int l = tid & 63, w = tid >> 6;
  const int wg = blockIdx.x;
  const int lr = l & 15, kg = l >> 4;
  const int col = w * 16 + lr;     // h-column this thread updates (and B-frag col)
  const int rbase = kg * 4;        // local batch rows rbase..rbase+3 (C-frag rows)

  // hoist Whh B-fragments: wf[gate][kslice], loop-invariant
  s16x8 wf[4][4];
#pragma unroll
  for (int gi = 0; gi < 4; ++gi)
#pragma unroll
    for (int kk = 0; kk < 4; ++kk) {
      const float* p = Whh + (size_t)(gi * 128 + col) * 128 + kk * 32 + kg * 8;
#pragma unroll
      for (int e = 0; e < 8; ++e) wf[gi][kk][e] = (short)f2bf(p[e]);
    }
  for (int i = tid; i < 4096; i += 512) ((unsigned short*)hb)[i] = 0;
  float c[4] = {0.f, 0.f, 0.f, 0.f};

  const float* pbase = pre + ((size_t)(wg * 16 + rbase)) * 512 + col;
  float pf[16];
#pragma unroll
  for (int gi = 0; gi < 4; ++gi)
#pragma unroll
    for (int e = 0; e < 4; ++e) pf[gi * 4 + e] = pbase[e * 512 + gi * 128];
  __syncthreads();

  for (int t = 0; t < T; ++t) {
    const unsigned short* hc = hb[t & 1];
    unsigned short* hn = hb[(t & 1) ^ 1];
    // A-fragments of h (prev step) from swizzled LDS
    s16x8 a[4];
#pragma unroll
    for (int kk = 0; kk < 4; ++kk) {
      const int byt = lr * 256 + ((kk * 64 + kg * 16) ^ ((lr & 7) << 4));
      a[kk] = *(const s16x8*)((const char*)hc + byt);
    }
    f32x4 acc[4];
#pragma unroll
    for (int gi = 0; gi < 4; ++gi)
      acc[gi] = (f32x4){pf[gi * 4], pf[gi * 4 + 1], pf[gi * 4 + 2], pf[gi * 4 + 3]};
    // prefetch pre[t+1] under compute
    float pfn[16];
    if (t + 1 < T) {
      const float* pb2 = pbase + (size_t)(t + 1) * 65536;
#pragma unroll
      for (int gi = 0; gi < 4; ++gi)
#pragma unroll
        for (int e = 0; e < 4; ++e) pfn[gi * 4 + e] = pb2[e * 512 + gi * 128];
    } else {
#pragma unroll
      for (int i2 = 0; i2 < 16; ++i2) pfn[i2] = 0.f;
    }
#pragma unroll
    for (int kk = 0; kk < 4; ++kk)
#pragma unroll
      for (int gi = 0; gi < 4; ++gi)
        acc[gi] = __builtin_amdgcn_mfma_f32_16x16x32_bf16(a[kk], wf[gi][kk], acc[gi], 0, 0, 0);
    // gates: PyTorch order i,f,g,o
#pragma unroll
    for (int e = 0; e < 4; ++e) {
      float gi_ = sigf(acc[0][e]);
      float gf  = sigf(acc[1][e]);
      float gg  = tanhf_(acc[2][e]);
      float go  = sigf(acc[3][e]);
      c[e] = gf * c[e] + gi_ * gg;
      float h = go * tanhf_(c[e]);
      unsigned short hu = f2bf(h);
      int row = rbase + e;
      int byt = row * 256 + ((col * 2) ^ ((row & 7) << 4));
      *(unsigned short*)((char*)hn + byt) = hu;
      hs[((size_t)t * 128 + wg * 16 + row) * 128 + col] = hu;
    }
#pragma unroll
    for (int i2 = 0; i2 < 16; ++i2) pf[i2] = pfn[i2];
    __syncthreads();
  }
}

// ---------------------------------------------------------------- decoder: 128 independent WGs, one batch row each
__global__ __launch_bounds__(512) void decoder_k(
    const unsigned short* __restrict__ kb, const unsigned short* __restrict__ vb,
    const unsigned short* __restrict__ W0, const unsigned short* __restrict__ Wh0,
    const unsigned short* __restrict__ Wi1, const unsigned short* __restrict__ Wh1,
    const unsigned short* __restrict__ Wqm, const unsigned short* __restrict__ Wom,
    const float* __restrict__ b0, const float* __restrict__ b1,
    const float* __restrict__ bq, const float* __restrict__ bo,
    const float* __restrict__ linW, const float* __restrict__ linb,
    float* __restrict__ out) {
  const int b = blockIdx.x;
  const int tid = threadIdx.x;
  const int l = tid & 63, wv = tid >> 6;
  __shared__ float xin[136];                       // [0..3]=y, [4..131]=ct, pad->0
  __shared__ float h0s[128], c0s[128], h1s[128], c1s[128];
  __shared__ float gb[512];
  __shared__ float qs[128];
  __shared__ float sc[4][512];
  __shared__ float red[32];
  __shared__ float mx4[4], is4[4];
  __shared__ float avp[16][32];
  __shared__ float ctv[128];
  __shared__ float ctl[128];
  for (int i = tid; i < 136; i += 512) xin[i] = 0.f;
  if (tid < 128) { h0s[tid] = 0.f; c0s[tid] = 0.f; h1s[tid] = 0.f; c1s[tid] = 0.f; }
  __syncthreads();

  for (int s = 0; s < 64; ++s) {
    // layer-0 gates: g[tid] = b0 + Wih0.xin + Whh0.h0
    {
      float acc = b0[tid];
      const s16x8* wr = (const s16x8*)(W0 + (size_t)tid * 136);
#pragma unroll
      for (int cc = 0; cc < 17; ++cc) {
        s16x8 wvv = wr[cc];
#pragma unroll
        for (int e = 0; e < 8; ++e) acc += xin[cc * 8 + e] * bf2f(wvv[e]);
      }
      const s16x8* w2 = (const s16x8*)(Wh0 + (size_t)tid * 128);
#pragma unroll
      for (int cc = 0; cc < 16; ++cc) {
        s16x8 wvv = w2[cc];
#pragma unroll
        for (int e = 0; e < 8; ++e) acc += h0s[cc * 8 + e] * bf2f(wvv[e]);
      }
      gb[tid] = acc;
    }
    __syncthreads();
    if (tid < 128) {
      float c = sigf(gb[128 + tid]) * c0s[tid] + sigf(gb[tid]) * tanhf_(gb[256 + tid]);
      c0s[tid] = c;
      h0s[tid] = sigf(gb[384 + tid]) * tanhf_(c);
    }
    __syncthreads();
    // layer-1 gates
    {
      float acc = b1[tid];
      const s16x8* w1 = (const s16x8*)(Wi1 + (size_t)tid * 128);
      const s16x8* w2 = (const s16x8*)(Wh1 + (size_t)tid * 128);
#pragma unroll
      for (int cc = 0; cc < 16; ++cc) {
        s16x8 a_ = w1[cc], b_ = w2[cc];
#pragma unroll
        for (int e = 0; e < 8; ++e) acc += h0s[cc * 8 + e] * bf2f(a_[e]) + h1s[cc * 8 + e] * bf2f(b_[e]);
      }
      gb[tid] = acc;
    }
    __syncthreads();
    if (tid < 128) {
      float c = sigf(gb[128 + tid]) * c1s[tid] + sigf(gb[tid]) * tanhf_(gb[256 + tid]);
      c1s[tid] = c;
      h1s[tid] = sigf(gb[384 + tid]) * tanhf_(c);
    }
    __syncthreads();
    // q = Wq.h1 + bq
    if (tid < 128) {
      float acc = bq[tid];
      const s16x8* wq = (const s16x8*)(Wqm + (size_t)tid * 128);
#pragma unroll
      for (int cc = 0; cc < 16; ++cc) {
        s16x8 wvv = wq[cc];
#pragma unroll
        for (int e = 0; e < 8; ++e) acc += h1s[cc * 8 + e] * bf2f(wvv[e]);
      }
      qs[tid] = acc;
    }
    __syncthreads();
    // scores: thread tid handles t = tid, all 4 heads (k row contiguous 256B)
    {
      const s16x8* kr = (const s16x8*)(kb + ((size_t)tid * 128 + b) * 128);
      float s4[4] = {0.f, 0.f, 0.f, 0.f};
#pragma unroll
      for (int cc = 0; cc < 16; ++cc) {
        s16x8 kvv = kr[cc];
#pragma unroll
        for (int e = 0; e < 8; ++e) s4[cc >> 2] += qs[cc * 8 + e] * bf2f(kvv[e]);
      }
      const float scale = 0.1767766952966369f;  // 1/sqrt(32)
#pragma unroll
      for (int h = 0; h < 4; ++h) {
        s4[h] *= scale;
        sc[h][tid] = s4[h];
        float m = s4[h];
#pragma unroll
        for (int off = 32; off > 0; off >>= 1) m = fmaxf(m, __shfl_xor(m, off));
        if (l == 0) red[wv * 4 + h] = m;
      }
    }
    __syncthreads();
    if (tid < 4) {
      float m = red[tid];
#pragma unroll
      for (int w2 = 1; w2 < 8; ++w2) m = fmaxf(m, red[w2 * 4 + tid]);
      mx4[tid] = m;
    }
    __syncthreads();
    {
#pragma unroll
      for (int h = 0; h < 4; ++h) {
        float p = __expf(sc[h][tid] - mx4[h]);
        sc[h][tid] = p;
#pragma unroll
        for (int off = 32; off > 0; off >>= 1) p += __shfl_xor(p, off);
        if (l == 0) red[wv * 4 + h] = p;
      }
    }
    __syncthreads();
    if (tid < 4) {
      float sm = 0.f;
#pragma unroll
      for (int w2 = 0; w2 < 8; ++w2) sm += red[w2 * 4 + tid];
      is4[tid] = 1.f / sm;
    }
    __syncthreads();
    // AV: thread -> (h, t-chunk, d); 128-long partial sums
    {
      const int h = tid >> 7, rem = tid & 127, tc = rem >> 5, d = rem & 31;
      float acc = 0.f;
      const unsigned short* vp = vb + ((size_t)(tc * 128) * 128 + b) * 128 + h * 32 + d;
#pragma unroll 4
      for (int tt = 0; tt < 128; ++tt)
        acc += sc[h][tc * 128 + tt] * bf2f((short)vp[(size_t)tt * 16384]);
      avp[h * 4 + tc][d] = acc;
    }
    __syncthreads();
    if (tid < 128) {
      const int h = tid >> 5, d = tid & 31;
      ctv[tid] = (avp[h * 4 + 0][d] + avp[h * 4 + 1][d] + avp[h * 4 + 2][d] + avp[h * 4 + 3][d]) * is4[h];
    }
    __syncthreads();
    // ct = Wo.ctv + bo ; also next step's xin[4..]
    if (tid < 128) {
      float acc = bo[tid];
      const s16x8* wo = (const s16x8*)(Wom + (size_t)tid * 128);
#pragma unroll
      for (int cc = 0; cc < 16; ++cc) {
        s16x8 wvv = wo[cc];
#pragma unroll
        for (int e = 0; e < 8; ++e) acc += ctv[cc * 8 + e] * bf2f(wvv[e]);
      }
      ctl[tid] = acc;
      xin[4 + tid] = acc;
    }
    __syncthreads();
    // y = [h1, ct] @ lin_W.T + lin_b  (4 outputs, one wave each)
    if (tid < 256) {
      const int o = tid >> 6, kk = tid & 63;
      const float* lw = linW + o * 256;
      float part = h1s[kk] * lw[kk] + h1s[kk + 64] * lw[kk + 64]
                 + ctl[kk] * lw[128 + kk] + ctl[kk + 64] * lw[192 + kk];
#pragma unroll
      for (int off = 32; off > 0; off >>= 1) part += __shfl_xor(part, off);
      if (kk == 0) {
        float yv = part + linb[o];
        out[((size_t)s * 128 + b) * 4 + o] = yv;
        xin[o] = yv;
      }
    }
    __syncthreads();
  }
}

// ---------------------------------------------------------------- launch
extern "C" void kernel_launch(void* const* d_in, const int* in_sizes, int n_in,
                              void* d_out, int out_size, void* d_ws, size_t ws_size,
                              hipStream_t stream) {
  (void)in_sizes; (void)n_in; (void)out_size; (void)ws_size;
  const float* x     = (const float*)d_in[0];
  const float* eWih0 = (const float*)d_in[1];
  const float* eWhh0 = (const float*)d_in[2];
  const float* eb0   = (const float*)d_in[3];
  const float* eWih1 = (const float*)d_in[4];
  const float* eWhh1 = (const float*)d_in[5];
  const float* eb1   = (const float*)d_in[6];
  const float* dWih0 = (const float*)d_in[7];
  const float* dWhh0 = (const float*)d_in[8];
  const float* db0   = (const float*)d_in[9];
  const float* dWih1 = (const float*)d_in[10];
  const float* dWhh1 = (const float*)d_in[11];
  const float* db1   = (const float*)d_in[12];
  const float* Wq    = (const float*)d_in[13];
  const float* bq    = (const float*)d_in[14];
  const float* Wk    = (const float*)d_in[15];
  const float* bk    = (const float*)d_in[16];
  const float* Wv    = (const float*)d_in[17];
  const float* bv    = (const float*)d_in[18];
  const float* Wo    = (const float*)d_in[19];
  const float* bo    = (const float*)d_in[20];
  const float* linW  = (const float*)d_in[21];
  const float* linb  = (const float*)d_in[22];

  char* w = (char*)d_ws;
  float* pre = (float*)w;
  size_t off = (size_t)65536 * 512 * 4;                                   // 128 MB (reused by both layers)
  unsigned short* hs0  = (unsigned short*)(w + off); off += (size_t)65536 * 128 * 2;
  unsigned short* enc  = (unsigned short*)(w + off); off += (size_t)65536 * 128 * 2;
  unsigned short* kbuf = (unsigned short*)(w + off); off += (size_t)65536 * 128 * 2;
  unsigned short* vbuf = (unsigned short*)(w + off); off += (size_t)65536 * 128 * 2;
  unsigned short* W0p  = (unsigned short*)(w + off); off += 512 * 136 * 2;
  unsigned short* Wh0d = (unsigned short*)(w + off); off += 512 * 128 * 2;
  unsigned short* Wi1d = (unsigned short*)(w + off); off += 512 * 128 * 2;
  unsigned short* Wh1d = (unsigned short*)(w + off); off += 512 * 128 * 2;
  unsigned short* Wqd  = (unsigned short*)(w + off); off += 128 * 128 * 2;
  unsigned short* Wod  = (unsigned short*)(w + off); off += 128 * 128 * 2;

  conv_pad<<<(512 * 136 + 255) / 256, 256, 0, stream>>>(dWih0, W0p, 512, 132, 136);
  conv_pad<<<(512 * 128 + 255) / 256, 256, 0, stream>>>(dWhh0, Wh0d, 512, 128, 128);
  conv_pad<<<(512 * 128 + 255) / 256, 256, 0, stream>>>(dWih1, Wi1d, 512, 128, 128);
  conv_pad<<<(512 * 128 + 255) / 256, 256, 0, stream>>>(dWhh1, Wh1d, 512, 128, 128);
  conv_pad<<<(128 * 128 + 255) / 256, 256, 0, stream>>>(Wq, Wqd, 128, 128, 128);
  conv_pad<<<(128 * 128 + 255) / 256, 256, 0, stream>>>(Wo, Wod, 128, 128, 128);

  // encoder
  gemm_bt<0, 0><<<dim3(4, 512), 256, 0, stream>>>((const void*)x, eWih0, eb0, (void*)pre, 65536, 512, 1024);
  lstm_scan<<<8, 512, 0, stream>>>(pre, eWhh0, hs0, 512);
  gemm_bt<1, 0><<<dim3(4, 512), 256, 0, stream>>>((const void*)hs0, eWih1, eb1, (void*)pre, 65536, 512, 128);
  lstm_scan<<<8, 512, 0, stream>>>(pre, eWhh1, enc, 512);
  // K/V projections
  gemm_bt<1, 1><<<dim3(1, 512), 256, 0, stream>>>((const void*)enc, Wk, bk, (void*)kbuf, 65536, 128, 128);
  gemm_bt<1, 1><<<dim3(1, 512), 256, 0, stream>>>((const void*)enc, Wv, bv, (void*)vbuf, 65536, 128, 128);
  // decoder
  decoder_k<<<128, 512, 0, stream>>>(kbuf, vbuf, W0p, Wh0d, Wi1d, Wh1d, Wqd, Wod,
                                     db0, db1, bq, bo, linW, linb, (float*)d_out);
}

// Round 3
// 12965.771 us; speedup vs baseline: 1.0012x; 1.0012x over previous
//
#include <hip/hip_runtime.h>
#include <hip/hip_bf16.h>

typedef __attribute__((ext_vector_type(8))) short s16x8;
typedef __attribute__((ext_vector_type(4))) float f32x4;

__device__ inline unsigned short f2bf(float f) {
  unsigned u = __builtin_bit_cast(unsigned, f);
  unsigned r = (u + 0x7FFFu + ((u >> 16) & 1u)) >> 16;  // RTNE
  return (unsigned short)r;
}
__device__ inline float bf2f(short v) {
  return __builtin_bit_cast(float, ((unsigned)(unsigned short)v) << 16);
}
__device__ inline float sigf(float x) { return 1.f / (1.f + __expf(-x)); }
__device__ inline float tanhf_(float x) { float e = __expf(2.f * x); return 1.f - 2.f / (e + 1.f); }

// ---------------------------------------------------------------- conv/pad
__global__ void conv_pad(const float* __restrict__ src, unsigned short* __restrict__ dst,
                         int rows, int scols, int dcols) {
  int i = blockIdx.x * 256 + threadIdx.x;
  if (i >= rows * dcols) return;
  int r = i / dcols, cc = i % dcols;
  dst[i] = (cc < scols) ? f2bf(src[(size_t)r * scols + cc]) : (unsigned short)0;
}

// ---------------------------------------------------------------- GEMM C = A @ B^T + bias
// A: [M,K] (f32 or bf16), B: [N,K] f32 (weights), C: [M,N] (f32 or bf16)
#define BM 128
#define BN 128
#define BKK 32

template<int A_BF16, int C_BF16>
__global__ __launch_bounds__(256) void gemm_bt(const void* __restrict__ Av,
    const float* __restrict__ B, const float* __restrict__ bias,
    void* __restrict__ Cv, int M, int N, int K) {
  __shared__ short sA[BM * BKK];
  __shared__ short sB[BN * BKK];
  const int tid = threadIdx.x;
  const int l = tid & 63;
  const int wid = tid >> 6;
  const int wr = wid >> 1, wc = wid & 1;
  const int lr = l & 15, kg = l >> 4;
  const int bn = blockIdx.x, bm = blockIdx.y;   // bn fastest -> A-tile L2 reuse
  const int arow = tid >> 1;
  const int acol = (tid & 1) * 16;

  f32x4 acc[4][4];
#pragma unroll
  for (int i = 0; i < 4; ++i)
#pragma unroll
    for (int j = 0; j < 4; ++j) acc[i][j] = (f32x4){0.f, 0.f, 0.f, 0.f};

  for (int kt = 0; kt < K; kt += BKK) {
    __syncthreads();
    if (A_BF16) {
      const unsigned short* src = (const unsigned short*)Av + (size_t)(bm * BM + arow) * K + kt + acol;
      *(s16x8*)&sA[arow * BKK + acol] = *(const s16x8*)src;
      *(s16x8*)&sA[arow * BKK + acol + 8] = *(const s16x8*)(src + 8);
    } else {
      const float* src = (const float*)Av + (size_t)(bm * BM + arow) * K + kt + acol;
      s16x8 v0, v1;
#pragma unroll
      for (int e = 0; e < 8; ++e) { v0[e] = (short)f2bf(src[e]); v1[e] = (short)f2bf(src[8 + e]); }
      *(s16x8*)&sA[arow * BKK + acol] = v0;
      *(s16x8*)&sA[arow * BKK + acol + 8] = v1;
    }
    {
      const float* src = B + (size_t)(bn * BN + arow) * K + kt + acol;
      s16x8 v0, v1;
#pragma unroll
      for (int e = 0; e < 8; ++e) { v0[e] = (short)f2bf(src[e]); v1[e] = (short)f2bf(src[8 + e]); }
      *(s16x8*)&sB[arow * BKK + acol] = v0;
      *(s16x8*)&sB[arow * BKK + acol + 8] = v1;
    }
    __syncthreads();
    s16x8 af[4], bfr[4];
#pragma unroll
    for (int mi = 0; mi < 4; ++mi)
      af[mi] = *(const s16x8*)&sA[(wr * 64 + mi * 16 + lr) * BKK + kg * 8];
#pragma unroll
    for (int ni = 0; ni < 4; ++ni)
      bfr[ni] = *(const s16x8*)&sB[(wc * 64 + ni * 16 + lr) * BKK + kg * 8];
#pragma unroll
    for (int mi = 0; mi < 4; ++mi)
#pragma unroll
      for (int ni = 0; ni < 4; ++ni)
        acc[mi][ni] = __builtin_amdgcn_mfma_f32_16x16x32_bf16(af[mi], bfr[ni], acc[mi][ni], 0, 0, 0);
  }
  const int r0 = bm * BM + wr * 64;
  const int c0 = bn * BN + wc * 64;
#pragma unroll
  for (int mi = 0; mi < 4; ++mi)
#pragma unroll
    for (int ni = 0; ni < 4; ++ni) {
      const int col = c0 + ni * 16 + lr;
      const float bv = bias[col];
#pragma unroll
      for (int e = 0; e < 4; ++e) {
        const int row = r0 + mi * 16 + kg * 4 + e;
        const float v = acc[mi][ni][e] + bv;
        if (C_BF16) ((unsigned short*)Cv)[(size_t)row * N + col] = f2bf(v);
        else        ((float*)Cv)[(size_t)row * N + col] = v;
      }
    }
}

// ---------------------------------------------------------------- LSTM scan (one layer)
// pre: [T][128][512] f32 (x@Wih.T + b precomputed), Whh: [512][128] f32, hs out: [T][128][128] bf16.
// 8 WGs x 512 threads; WG owns 16 batch rows for the whole scan. Whh fragments hoisted to VGPRs.
__global__ __launch_bounds__(512) void lstm_scan(const float* __restrict__ pre,
    const float* __restrict__ Whh, unsigned short* __restrict__ hs, int T) {
  __shared__ unsigned short hb[2][2048];   // double-buffered h tile [16][128] bf16, XOR-swizzled
  const int tid = threadIdx.x;
  const int l = tid & 63, w = tid >> 6;
  const int wg = blockIdx.x;
  const int lr = l & 15, kg = l >> 4;
  const int col = w * 16 + lr;     // h-column this thread updates (and B-frag col)
  const int rbase = kg * 4;        // local batch rows rbase..rbase+3 (C-frag rows)

  // hoist Whh B-fragments: wf[gate][kslice], loop-invariant
  s16x8 wf[4][4];
#pragma unroll
  for (int gi = 0; gi < 4; ++gi)
#pragma unroll
    for (int kk = 0; kk < 4; ++kk) {
      const float* p = Whh + (size_t)(gi * 128 + col) * 128 + kk * 32 + kg * 8;
#pragma unroll
      for (int e = 0; e < 8; ++e) wf[gi][kk][e] = (short)f2bf(p[e]);
    }
  for (int i = tid; i < 4096; i += 512) ((unsigned short*)hb)[i] = 0;
  float c[4] = {0.f, 0.f, 0.f, 0.f};

  const float* pbase = pre + ((size_t)(wg * 16 + rbase)) * 512 + col;
  float pf[16];
#pragma unroll
  for (int gi = 0; gi < 4; ++gi)
#pragma unroll
    for (int e = 0; e < 4; ++e) pf[gi * 4 + e] = pbase[e * 512 + gi * 128];
  __syncthreads();

  for (int t = 0; t < T; ++t) {
    const unsigned short* hc = hb[t & 1];
    unsigned short* hn = hb[(t & 1) ^ 1];
    // A-fragments of h (prev step) from swizzled LDS
    s16x8 a[4];
#pragma unroll
    for (int kk = 0; kk < 4; ++kk) {
      const int byt = lr * 256 + ((kk * 64 + kg * 16) ^ ((lr & 7) << 4));
      a[kk] = *(const s16x8*)((const char*)hc + byt);
    }
    f32x4 acc[4];
#pragma unroll
    for (int gi = 0; gi < 4; ++gi)
      acc[gi] = (f32x4){pf[gi * 4], pf[gi * 4 + 1], pf[gi * 4 + 2], pf[gi * 4 + 3]};
    // prefetch pre[t+1] under compute
    float pfn[16];
    if (t + 1 < T) {
      const float* pb2 = pbase + (size_t)(t + 1) * 65536;
#pragma unroll
      for (int gi = 0; gi < 4; ++gi)
#pragma unroll
        for (int e = 0; e < 4; ++e) pfn[gi * 4 + e] = pb2[e * 512 + gi * 128];
    } else {
#pragma unroll
      for (int i2 = 0; i2 < 16; ++i2) pfn[i2] = 0.f;
    }
#pragma unroll
    for (int kk = 0; kk < 4; ++kk)
#pragma unroll
      for (int gi = 0; gi < 4; ++gi)
        acc[gi] = __builtin_amdgcn_mfma_f32_16x16x32_bf16(a[kk], wf[gi][kk], acc[gi], 0, 0, 0);
    // gates: PyTorch order i,f,g,o
#pragma unroll
    for (int e = 0; e < 4; ++e) {
      float gi_ = sigf(acc[0][e]);
      float gf  = sigf(acc[1][e]);
      float gg  = tanhf_(acc[2][e]);
      float go  = sigf(acc[3][e]);
      c[e] = gf * c[e] + gi_ * gg;
      float h = go * tanhf_(c[e]);
      unsigned short hu = f2bf(h);
      int row = rbase + e;
      int byt = row * 256 + ((col * 2) ^ ((row & 7) << 4));
      *(unsigned short*)((char*)hn + byt) = hu;
      hs[((size_t)t * 128 + wg * 16 + row) * 128 + col] = hu;
    }
#pragma unroll
    for (int i2 = 0; i2 < 16; ++i2) pf[i2] = pfn[i2];
    __syncthreads();
  }
}

// ---------------------------------------------------------------- decoder: 128 independent WGs, one batch row each
__global__ __launch_bounds__(512) void decoder_k(
    const unsigned short* __restrict__ kb, const unsigned short* __restrict__ vb,
    const unsigned short* __restrict__ W0, const unsigned short* __restrict__ Wh0,
    const unsigned short* __restrict__ Wi1, const unsigned short* __restrict__ Wh1,
    const unsigned short* __restrict__ Wqm, const unsigned short* __restrict__ Wom,
    const float* __restrict__ b0, const float* __restrict__ b1,
    const float* __restrict__ bq, const float* __restrict__ bo,
    const float* __restrict__ linW, const float* __restrict__ linb,
    float* __restrict__ out) {
  const int b = blockIdx.x;
  const int tid = threadIdx.x;
  const int l = tid & 63, wv = tid >> 6;
  __shared__ float xin[136];                       // [0..3]=y, [4..131]=ct, pad->0
  __shared__ float h0s[128], c0s[128], h1s[128], c1s[128];
  __shared__ float gb[512];
  __shared__ float qs[128];
  __shared__ float sc[4][512];
  __shared__ float red[32];
  __shared__ float mx4[4], is4[4];
  __shared__ float avp[16][32];
  __shared__ float ctv[128];
  __shared__ float ctl[128];
  for (int i = tid; i < 136; i += 512) xin[i] = 0.f;
  if (tid < 128) { h0s[tid] = 0.f; c0s[tid] = 0.f; h1s[tid] = 0.f; c1s[tid] = 0.f; }
  __syncthreads();

  for (int s = 0; s < 64; ++s) {
    // layer-0 gates: g[tid] = b0 + Wih0.xin + Whh0.h0
    {
      float acc = b0[tid];
      const s16x8* wr = (const s16x8*)(W0 + (size_t)tid * 136);
#pragma unroll
      for (int cc = 0; cc < 17; ++cc) {
        s16x8 wvv = wr[cc];
#pragma unroll
        for (int e = 0; e < 8; ++e) acc += xin[cc * 8 + e] * bf2f(wvv[e]);
      }
      const s16x8* w2 = (const s16x8*)(Wh0 + (size_t)tid * 128);
#pragma unroll
      for (int cc = 0; cc < 16; ++cc) {
        s16x8 wvv = w2[cc];
#pragma unroll
        for (int e = 0; e < 8; ++e) acc += h0s[cc * 8 + e] * bf2f(wvv[e]);
      }
      gb[tid] = acc;
    }
    __syncthreads();
    if (tid < 128) {
      float c = sigf(gb[128 + tid]) * c0s[tid] + sigf(gb[tid]) * tanhf_(gb[256 + tid]);
      c0s[tid] = c;
      h0s[tid] = sigf(gb[384 + tid]) * tanhf_(c);
    }
    __syncthreads();
    // layer-1 gates
    {
      float acc = b1[tid];
      const s16x8* w1 = (const s16x8*)(Wi1 + (size_t)tid * 128);
      const s16x8* w2 = (const s16x8*)(Wh1 + (size_t)tid * 128);
#pragma unroll
      for (int cc = 0; cc < 16; ++cc) {
        s16x8 a_ = w1[cc], b_ = w2[cc];
#pragma unroll
        for (int e = 0; e < 8; ++e) acc += h0s[cc * 8 + e] * bf2f(a_[e]) + h1s[cc * 8 + e] * bf2f(b_[e]);
      }
      gb[tid] = acc;
    }
    __syncthreads();
    if (tid < 128) {
      float c = sigf(gb[128 + tid]) * c1s[tid] + sigf(gb[tid]) * tanhf_(gb[256 + tid]);
      c1s[tid] = c;
      h1s[tid] = sigf(gb[384 + tid]) * tanhf_(c);
    }
    __syncthreads();
    // q = Wq.h1 + bq
    if (tid < 128) {
      float acc = bq[tid];
      const s16x8* wq = (const s16x8*)(Wqm + (size_t)tid * 128);
#pragma unroll
      for (int cc = 0; cc < 16; ++cc) {
        s16x8 wvv = wq[cc];
#pragma unroll
        for (int e = 0; e < 8; ++e) acc += h1s[cc * 8 + e] * bf2f(wvv[e]);
      }
      qs[tid] = acc;
    }
    __syncthreads();
    // scores: thread tid handles t = tid, all 4 heads (k row contiguous 256B)
    {
      const s16x8* kr = (const s16x8*)(kb + ((size_t)tid * 128 + b) * 128);
      float s4[4] = {0.f, 0.f, 0.f, 0.f};
#pragma unroll
      for (int cc = 0; cc < 16; ++cc) {
        s16x8 kvv = kr[cc];
#pragma unroll
        for (int e = 0; e < 8; ++e) s4[cc >> 2] += qs[cc * 8 + e] * bf2f(kvv[e]);
      }
      const float scale = 0.1767766952966369f;  // 1/sqrt(32)
#pragma unroll
      for (int h = 0; h < 4; ++h) {
        s4[h] *= scale;
        sc[h][tid] = s4[h];
        float m = s4[h];
#pragma unroll
        for (int off = 32; off > 0; off >>= 1) m = fmaxf(m, __shfl_xor(m, off));
        if (l == 0) red[wv * 4 + h] = m;
      }
    }
    __syncthreads();
    if (tid < 4) {
      float m = red[tid];
#pragma unroll
      for (int w2 = 1; w2 < 8; ++w2) m = fmaxf(m, red[w2 * 4 + tid]);
      mx4[tid] = m;
    }
    __syncthreads();
    {
#pragma unroll
      for (int h = 0; h < 4; ++h) {
        float p = __expf(sc[h][tid] - mx4[h]);
        sc[h][tid] = p;
#pragma unroll
        for (int off = 32; off > 0; off >>= 1) p += __shfl_xor(p, off);
        if (l == 0) red[wv * 4 + h] = p;
      }
    }
    __syncthreads();
    if (tid < 4) {
      float sm = 0.f;
#pragma unroll
      for (int w2 = 0; w2 < 8; ++w2) sm += red[w2 * 4 + tid];
      is4[tid] = 1.f / sm;
    }
    __syncthreads();
    // AV: thread -> (h, t-chunk, d); 128-long partial sums
    {
      const int h = tid >> 7, rem = tid & 127, tc = rem >> 5, d = rem & 31;
      float acc = 0.f;
      const unsigned short* vp = vb + ((size_t)(tc * 128) * 128 + b) * 128 + h * 32 + d;
#pragma unroll 4
      for (int tt = 0; tt < 128; ++tt)
        acc += sc[h][tc * 128 + tt] * bf2f((short)vp[(size_t)tt * 16384]);
      avp[h * 4 + tc][d] = acc;
    }
    __syncthreads();
    if (tid < 128) {
      const int h = tid >> 5, d = tid & 31;
      ctv[tid] = (avp[h * 4 + 0][d] + avp[h * 4 + 1][d] + avp[h * 4 + 2][d] + avp[h * 4 + 3][d]) * is4[h];
    }
    __syncthreads();
    // ct = Wo.ctv + bo ; also next step's xin[4..]
    if (tid < 128) {
      float acc = bo[tid];
      const s16x8* wo = (const s16x8*)(Wom + (size_t)tid * 128);
#pragma unroll
      for (int cc = 0; cc < 16; ++cc) {
        s16x8 wvv = wo[cc];
#pragma unroll
        for (int e = 0; e < 8; ++e) acc += ctv[cc * 8 + e] * bf2f(wvv[e]);
      }
      ctl[tid] = acc;
      xin[4 + tid] = acc;
    }
    __syncthreads();
    // y = [h1, ct] @ lin_W.T + lin_b  (4 outputs, one wave each)
    if (tid < 256) {
      const int o = tid >> 6, kk = tid & 63;
      const float* lw = linW + o * 256;
      float part = h1s[kk] * lw[kk] + h1s[kk + 64] * lw[kk + 64]
                 + ctl[kk] * lw[128 + kk] + ctl[kk + 64] * lw[192 + kk];
#pragma unroll
      for (int off = 32; off > 0; off >>= 1) part += __shfl_xor(part, off);
      if (kk == 0) {
        float yv = part + linb[o];
        out[((size_t)s * 128 + b) * 4 + o] = yv;
        xin[o] = yv;
      }
    }
    __syncthreads();
  }
}

// ---------------------------------------------------------------- launch
extern "C" void kernel_launch(void* const* d_in, const int* in_sizes, int n_in,
                              void* d_out, int out_size, void* d_ws, size_t ws_size,
                              hipStream_t stream) {
  (void)in_sizes; (void)n_in; (void)out_size; (void)ws_size;
  const float* x     = (const float*)d_in[0];
  const float* eWih0 = (const float*)d_in[1];
  const float* eWhh0 = (const float*)d_in[2];
  const float* eb0   = (const float*)d_in[3];
  const float* eWih1 = (const float*)d_in[4];
  const float* eWhh1 = (const float*)d_in[5];
  const float* eb1   = (const float*)d_in[6];
  const float* dWih0 = (const float*)d_in[7];
  const float* dWhh0 = (const float*)d_in[8];
  const float* db0   = (const float*)d_in[9];
  const float* dWih1 = (const float*)d_in[10];
  const float* dWhh1 = (const float*)d_in[11];
  const float* db1   = (const float*)d_in[12];
  const float* Wq    = (const float*)d_in[13];
  const float* bq    = (const float*)d_in[14];
  const float* Wk    = (const float*)d_in[15];
  const float* bk    = (const float*)d_in[16];
  const float* Wv    = (const float*)d_in[17];
  const float* bv    = (const float*)d_in[18];
  const float* Wo    = (const float*)d_in[19];
  const float* bo    = (const float*)d_in[20];
  const float* linW  = (const float*)d_in[21];
  const float* linb  = (const float*)d_in[22];

  char* w = (char*)d_ws;
  float* pre = (float*)w;
  size_t off = (size_t)65536 * 512 * 4;                                   // 128 MB (reused by both layers)
  unsigned short* hs0  = (unsigned short*)(w + off); off += (size_t)65536 * 128 * 2;
  unsigned short* enc  = (unsigned short*)(w + off); off += (size_t)65536 * 128 * 2;
  unsigned short* kbuf = (unsigned short*)(w + off); off += (size_t)65536 * 128 * 2;
  unsigned short* vbuf = (unsigned short*)(w + off); off += (size_t)65536 * 128 * 2;
  unsigned short* W0p  = (unsigned short*)(w + off); off += 512 * 136 * 2;
  unsigned short* Wh0d = (unsigned short*)(w + off); off += 512 * 128 * 2;
  unsigned short* Wi1d = (unsigned short*)(w + off); off += 512 * 128 * 2;
  unsigned short* Wh1d = (unsigned short*)(w + off); off += 512 * 128 * 2;
  unsigned short* Wqd  = (unsigned short*)(w + off); off += 128 * 128 * 2;
  unsigned short* Wod  = (unsigned short*)(w + off); off += 128 * 128 * 2;

  conv_pad<<<(512 * 136 + 255) / 256, 256, 0, stream>>>(dWih0, W0p, 512, 132, 136);
  conv_pad<<<(512 * 128 + 255) / 256, 256, 0, stream>>>(dWhh0, Wh0d, 512, 128, 128);
  conv_pad<<<(512 * 128 + 255) / 256, 256, 0, stream>>>(dWih1, Wi1d, 512, 128, 128);
  conv_pad<<<(512 * 128 + 255) / 256, 256, 0, stream>>>(dWhh1, Wh1d, 512, 128, 128);
  conv_pad<<<(128 * 128 + 255) / 256, 256, 0, stream>>>(Wq, Wqd, 128, 128, 128);
  conv_pad<<<(128 * 128 + 255) / 256, 256, 0, stream>>>(Wo, Wod, 128, 128, 128);

  // encoder
  gemm_bt<0, 0><<<dim3(4, 512), 256, 0, stream>>>((const void*)x, eWih0, eb0, (void*)pre, 65536, 512, 1024);
  lstm_scan<<<8, 512, 0, stream>>>(pre, eWhh0, hs0, 512);
  gemm_bt<1, 0><<<dim3(4, 512), 256, 0, stream>>>((const void*)hs0, eWih1, eb1, (void*)pre, 65536, 512, 128);
  lstm_scan<<<8, 512, 0, stream>>>(pre, eWhh1, enc, 512);
  // K/V projections
  gemm_bt<1, 1><<<dim3(1, 512), 256, 0, stream>>>((const void*)enc, Wk, bk, (void*)kbuf, 65536, 128, 128);
  gemm_bt<1, 1><<<dim3(1, 512), 256, 0, stream>>>((const void*)enc, Wv, bv, (void*)vbuf, 65536, 128, 128);
  // decoder
  decoder_k<<<128, 512, 0, stream>>>(kbuf, vbuf, W0p, Wh0d, Wi1d, Wh1d, Wqd, Wod,
                                     db0, db1, bq, bo, linW, linb, (float*)d_out);
}

// Round 4
// 8811.867 us; speedup vs baseline: 1.4732x; 1.4714x over previous
//
#include <hip/hip_runtime.h>
#include <hip/hip_bf16.h>

typedef __attribute__((ext_vector_type(8))) short s16x8;
typedef __attribute__((ext_vector_type(4))) float f32x4;

__device__ inline unsigned short f2bf(float f) {
  unsigned u = __builtin_bit_cast(unsigned, f);
  unsigned r = (u + 0x7FFFu + ((u >> 16) & 1u)) >> 16;  // RTNE
  return (unsigned short)r;
}
__device__ inline float bf2f(short v) {
  return __builtin_bit_cast(float, ((unsigned)(unsigned short)v) << 16);
}
__device__ inline float sigf(float x) { return 1.f / (1.f + __expf(-x)); }
__device__ inline float tanhf_(float x) { float e = __expf(2.f * x); return 1.f - 2.f / (e + 1.f); }

__device__ inline unsigned long long aload64(const unsigned long long* p) {
  return __hip_atomic_load(p, __ATOMIC_RELAXED, __HIP_MEMORY_SCOPE_AGENT);
}
__device__ inline float aloadf(const float* p) {
  return __hip_atomic_load(p, __ATOMIC_RELAXED, __HIP_MEMORY_SCOPE_AGENT);
}
__device__ inline void astoref(float* p, float v) {
  __hip_atomic_store(p, v, __ATOMIC_RELAXED, __HIP_MEMORY_SCOPE_AGENT);
}

// ---------------------------------------------------------------- conv/pad
__global__ void conv_pad(const float* __restrict__ src, unsigned short* __restrict__ dst,
                         int rows, int scols, int dcols) {
  int i = blockIdx.x * 256 + threadIdx.x;
  if (i >= rows * dcols) return;
  int r = i / dcols, cc = i % dcols;
  dst[i] = (cc < scols) ? f2bf(src[(size_t)r * scols + cc]) : (unsigned short)0;
}

// ---------------------------------------------------------------- GEMM C = A @ B^T + bias
#define BM 128
#define BN 128
#define BKK 32

template<int A_BF16, int C_BF16>
__global__ __launch_bounds__(256) void gemm_bt(const void* __restrict__ Av,
    const float* __restrict__ B, const float* __restrict__ bias,
    void* __restrict__ Cv, int M, int N, int K) {
  __shared__ short sA[BM * BKK];
  __shared__ short sB[BN * BKK];
  const int tid = threadIdx.x;
  const int l = tid & 63;
  const int wid = tid >> 6;
  const int wr = wid >> 1, wc = wid & 1;
  const int lr = l & 15, kg = l >> 4;
  const int bn = blockIdx.x, bm = blockIdx.y;
  const int arow = tid >> 1;
  const int acol = (tid & 1) * 16;

  f32x4 acc[4][4];
#pragma unroll
  for (int i = 0; i < 4; ++i)
#pragma unroll
    for (int j = 0; j < 4; ++j) acc[i][j] = (f32x4){0.f, 0.f, 0.f, 0.f};

  for (int kt = 0; kt < K; kt += BKK) {
    __syncthreads();
    if (A_BF16) {
      const unsigned short* src = (const unsigned short*)Av + (size_t)(bm * BM + arow) * K + kt + acol;
      *(s16x8*)&sA[arow * BKK + acol] = *(const s16x8*)src;
      *(s16x8*)&sA[arow * BKK + acol + 8] = *(const s16x8*)(src + 8);
    } else {
      const float* src = (const float*)Av + (size_t)(bm * BM + arow) * K + kt + acol;
      s16x8 v0, v1;
#pragma unroll
      for (int e = 0; e < 8; ++e) { v0[e] = (short)f2bf(src[e]); v1[e] = (short)f2bf(src[8 + e]); }
      *(s16x8*)&sA[arow * BKK + acol] = v0;
      *(s16x8*)&sA[arow * BKK + acol + 8] = v1;
    }
    {
      const float* src = B + (size_t)(bn * BN + arow) * K + kt + acol;
      s16x8 v0, v1;
#pragma unroll
      for (int e = 0; e < 8; ++e) { v0[e] = (short)f2bf(src[e]); v1[e] = (short)f2bf(src[8 + e]); }
      *(s16x8*)&sB[arow * BKK + acol] = v0;
      *(s16x8*)&sB[arow * BKK + acol + 8] = v1;
    }
    __syncthreads();
    s16x8 af[4], bfr[4];
#pragma unroll
    for (int mi = 0; mi < 4; ++mi)
      af[mi] = *(const s16x8*)&sA[(wr * 64 + mi * 16 + lr) * BKK + kg * 8];
#pragma unroll
    for (int ni = 0; ni < 4; ++ni)
      bfr[ni] = *(const s16x8*)&sB[(wc * 64 + ni * 16 + lr) * BKK + kg * 8];
#pragma unroll
    for (int mi = 0; mi < 4; ++mi)
#pragma unroll
      for (int ni = 0; ni < 4; ++ni)
        acc[mi][ni] = __builtin_amdgcn_mfma_f32_16x16x32_bf16(af[mi], bfr[ni], acc[mi][ni], 0, 0, 0);
  }
  const int r0 = bm * BM + wr * 64;
  const int c0 = bn * BN + wc * 64;
#pragma unroll
  for (int mi = 0; mi < 4; ++mi)
#pragma unroll
    for (int ni = 0; ni < 4; ++ni) {
      const int col = c0 + ni * 16 + lr;
      const float bv = bias[col];
#pragma unroll
      for (int e = 0; e < 4; ++e) {
        const int row = r0 + mi * 16 + kg * 4 + e;
        const float v = acc[mi][ni][e] + bv;
        if (C_BF16) ((unsigned short*)Cv)[(size_t)row * N + col] = f2bf(v);
        else        ((float*)Cv)[(size_t)row * N + col] = v;
      }
    }
}

// ---------------------------------------------------------------- encoder LSTM scan
__global__ __launch_bounds__(512) void lstm_scan(const float* __restrict__ pre,
    const float* __restrict__ Whh, unsigned short* __restrict__ hs, int T) {
  __shared__ unsigned short hb[2][2048];
  const int tid = threadIdx.x;
  const int l = tid & 63, w = tid >> 6;
  const int wg = blockIdx.x;
  const int lr = l & 15, kg = l >> 4;
  const int col = w * 16 + lr;
  const int rbase = kg * 4;

  s16x8 wf[4][4];
#pragma unroll
  for (int gi = 0; gi < 4; ++gi)
#pragma unroll
    for (int kk = 0; kk < 4; ++kk) {
      const float* p = Whh + (size_t)(gi * 128 + col) * 128 + kk * 32 + kg * 8;
#pragma unroll
      for (int e = 0; e < 8; ++e) wf[gi][kk][e] = (short)f2bf(p[e]);
    }
  for (int i = tid; i < 4096; i += 512) ((unsigned short*)hb)[i] = 0;
  float c[4] = {0.f, 0.f, 0.f, 0.f};

  const float* pbase = pre + ((size_t)(wg * 16 + rbase)) * 512 + col;
  float pf[16];
#pragma unroll
  for (int gi = 0; gi < 4; ++gi)
#pragma unroll
    for (int e = 0; e < 4; ++e) pf[gi * 4 + e] = pbase[e * 512 + gi * 128];
  __syncthreads();

  for (int t = 0; t < T; ++t) {
    const unsigned short* hc = hb[t & 1];
    unsigned short* hn = hb[(t & 1) ^ 1];
    s16x8 a[4];
#pragma unroll
    for (int kk = 0; kk < 4; ++kk) {
      const int byt = lr * 256 + ((kk * 64 + kg * 16) ^ ((lr & 7) << 4));
      a[kk] = *(const s16x8*)((const char*)hc + byt);
    }
    f32x4 acc[4];
#pragma unroll
    for (int gi = 0; gi < 4; ++gi)
      acc[gi] = (f32x4){pf[gi * 4], pf[gi * 4 + 1], pf[gi * 4 + 2], pf[gi * 4 + 3]};
    float pfn[16];
    if (t + 1 < T) {
      const float* pb2 = pbase + (size_t)(t + 1) * 65536;
#pragma unroll
      for (int gi = 0; gi < 4; ++gi)
#pragma unroll
        for (int e = 0; e < 4; ++e) pfn[gi * 4 + e] = pb2[e * 512 + gi * 128];
    } else {
#pragma unroll
      for (int i2 = 0; i2 < 16; ++i2) pfn[i2] = 0.f;
    }
#pragma unroll
    for (int kk = 0; kk < 4; ++kk)
#pragma unroll
      for (int gi = 0; gi < 4; ++gi)
        acc[gi] = __builtin_amdgcn_mfma_f32_16x16x32_bf16(a[kk], wf[gi][kk], acc[gi], 0, 0, 0);
#pragma unroll
    for (int e = 0; e < 4; ++e) {
      float gi_ = sigf(acc[0][e]);
      float gf  = sigf(acc[1][e]);
      float gg  = tanhf_(acc[2][e]);
      float go  = sigf(acc[3][e]);
      c[e] = gf * c[e] + gi_ * gg;
      float h = go * tanhf_(c[e]);
      unsigned short hu = f2bf(h);
      int row = rbase + e;
      int byt = row * 256 + ((col * 2) ^ ((row & 7) << 4));
      *(unsigned short*)((char*)hn + byt) = hu;
      hs[((size_t)t * 128 + wg * 16 + row) * 128 + col] = hu;
    }
#pragma unroll
    for (int i2 = 0; i2 < 16; ++i2) pf[i2] = pfn[i2];
    __syncthreads();
  }
}

// ---------------------------------------------------------------- persistent decoder
// 256 WGs (1/CU). WG g: b=g>>1, half=g&1 holds K/V[b, heads half*2..half*2+1] in LDS.
// WGs 0-7: layer0 + Wo/lin (16 b each, weights in VGPRs). WGs 8-15: layer1 + Wq.
// Cross-WG data via agent-scope atomics; per-step counters cnt_h0/cnt_q/cnt_ctv.

__device__ __forceinline__ void attn_step(
    int s, int b, int half, int tid, int l, int wv,
    unsigned* cnt_q, unsigned* cnt_cv,
    const float* qg, float* ctvg,
    const unsigned short* Kl, const unsigned short* Vl,
    float* sc, float* qx, float* red, float* mxs, float* isl)
{
  if (tid == 0) {
    while (__hip_atomic_load(cnt_q + s, __ATOMIC_ACQUIRE, __HIP_MEMORY_SCOPE_AGENT) < 8u)
      __builtin_amdgcn_s_sleep(2);
  }
  __syncthreads();
  if (tid < 64) qx[tid] = aloadf(&qg[(size_t)b * 128 + half * 64 + tid]);
  __syncthreads();
  const int t = tid;
  float s2[2] = {0.f, 0.f};
#pragma unroll
  for (int c = 0; c < 8; ++c) {
    const s16x8 kv = *(const s16x8*)((const char*)Kl + t * 128 + (((c + t) & 7) << 4));
    float d = 0.f;
#pragma unroll
    for (int e = 0; e < 8; ++e) d += qx[c * 8 + e] * bf2f(kv[e]);
    s2[c >> 2] += d;
  }
  const float scale = 0.1767766952966369f;  // 1/sqrt(32)
  s2[0] *= scale; s2[1] *= scale;
#pragma unroll
  for (int hh = 0; hh < 2; ++hh) {
    float m = s2[hh];
#pragma unroll
    for (int off = 32; off > 0; off >>= 1) m = fmaxf(m, __shfl_xor(m, off));
    if (l == 0) red[hh * 8 + wv] = m;
  }
  __syncthreads();
  if (tid < 2) {
    float m = red[tid * 8];
#pragma unroll
    for (int w2 = 1; w2 < 8; ++w2) m = fmaxf(m, red[tid * 8 + w2]);
    mxs[tid] = m;
  }
  __syncthreads();
#pragma unroll
  for (int hh = 0; hh < 2; ++hh) {
    float p = __expf(s2[hh] - mxs[hh]);
    sc[hh * 512 + t] = p;
    float ps = p;
#pragma unroll
    for (int off = 32; off > 0; off >>= 1) ps += __shfl_xor(ps, off);
    if (l == 0) red[16 + hh * 8 + wv] = ps;
  }
  __syncthreads();
  if (tid < 2) {
    float sm = red[16 + tid * 8];
#pragma unroll
    for (int w2 = 1; w2 < 8; ++w2) sm += red[16 + tid * 8 + w2];
    isl[tid] = 1.f / sm;
  }
  __syncthreads();
  {
    const int hh = tid >> 8, dg = (tid >> 6) & 3, tc = tid & 63;
    const int c = hh * 4 + dg;
    float a8[8] = {0.f, 0.f, 0.f, 0.f, 0.f, 0.f, 0.f, 0.f};
#pragma unroll
    for (int tt = 0; tt < 8; ++tt) {
      const int tr = tc * 8 + ((tt + tc) & 7);
      const s16x8 vv = *(const s16x8*)((const char*)Vl + tr * 128 + (((c + tr) & 7) << 4));
      const float p = sc[hh * 512 + tr];
#pragma unroll
      for (int e = 0; e < 8; ++e) a8[e] += p * bf2f(vv[e]);
    }
#pragma unroll
    for (int off = 32; off > 0; off >>= 1)
#pragma unroll
      for (int e = 0; e < 8; ++e) a8[e] += __shfl_xor(a8[e], off);
    if (tc == 0) {
      const float iv = isl[hh];
#pragma unroll
      for (int e = 0; e < 8; ++e)
        astoref(&ctvg[(size_t)b * 128 + half * 64 + c * 8 + e], a8[e] * iv);
    }
  }
  __syncthreads();
  if (tid == 0)
    __hip_atomic_fetch_add(cnt_cv + s, 1u, __ATOMIC_RELEASE, __HIP_MEMORY_SCOPE_AGENT);
}

#define DEC_SMEM 161280

__global__ void __launch_bounds__(512, 2) decoder_persist(
    const unsigned short* __restrict__ kb, const unsigned short* __restrict__ vb,
    const unsigned short* __restrict__ W0p, const unsigned short* __restrict__ Wh0,
    const unsigned short* __restrict__ Wi1, const unsigned short* __restrict__ Wh1,
    const unsigned short* __restrict__ Wqd, const unsigned short* __restrict__ Wod,
    const float* __restrict__ b0, const float* __restrict__ b1,
    const float* __restrict__ bq, const float* __restrict__ bo,
    const float* __restrict__ linW, const float* __restrict__ linb,
    float* __restrict__ qg, float* __restrict__ h0g, float* __restrict__ h1g,
    float* __restrict__ ctvg, unsigned* __restrict__ cnts, float* __restrict__ out)
{
  extern __shared__ char smem[];
  unsigned short* Kl = (unsigned short*)smem;              // [512][64] skewed
  unsigned short* Vl = (unsigned short*)(smem + 65536);    // [512][64] skewed
  float* sc   = (float*)(smem + 131072);                   // [2][512]
  float* qx   = (float*)(smem + 135168);                   // [64]
  float* red  = (float*)(smem + 135424);                   // [32]
  float* mxs  = (float*)(smem + 135552);                   // [2]
  float* isl  = (float*)(smem + 135560);                   // [2]
  unsigned short* xint  = (unsigned short*)(smem + 135680);// [16][160] linear
  unsigned short* htile = (unsigned short*)(smem + 140800);// [16][128] linear
  float* scratch  = (float*)(smem + 144896);               // [2048]
  float* scratch2 = (float*)(smem + 153088);               // [2048]

  const int g = blockIdx.x;
  const int tid = threadIdx.x;
  const int b = g >> 1, half = g & 1;
  const int l = tid & 63, wv = tid >> 6;
  const int lr = l & 15, kg = l >> 4;
  const int col = wv * 16 + lr;
  const int rbase = kg * 4;
  unsigned* cnt_h0 = cnts;
  unsigned* cnt_q  = cnts + 64;
  unsigned* cnt_cv = cnts + 128;

  // one-time K/V load into LDS (row t: 8 16B octets, skew slot=(c+t)&7)
  {
    const int t = tid;
    const unsigned short* krow = kb + ((size_t)t * 128 + b) * 128 + half * 64;
    const unsigned short* vrow = vb + ((size_t)t * 128 + b) * 128 + half * 64;
#pragma unroll
    for (int c = 0; c < 8; ++c) {
      const s16x8 kv = *(const s16x8*)(krow + c * 8);
      const s16x8 vv = *(const s16x8*)(vrow + c * 8);
      const int sl = ((c + t) & 7) << 4;
      *(s16x8*)((char*)Kl + t * 128 + sl) = kv;
      *(s16x8*)((char*)Vl + t * 128 + sl) = vv;
    }
  }

  if (g < 8) {
    // ---- layer0 + Wo + lin owner for b in [g*16, g*16+16)
    const int b016 = g * 16;
    s16x8 wf0[4][5], wfh[4][4];
    float b0v[4], c0r[4];
#pragma unroll
    for (int gi = 0; gi < 4; ++gi) {
#pragma unroll
      for (int kk = 0; kk < 5; ++kk)
        wf0[gi][kk] = *(const s16x8*)(W0p + (size_t)(gi * 128 + col) * 160 + kk * 32 + kg * 8);
#pragma unroll
      for (int kk = 0; kk < 4; ++kk)
        wfh[gi][kk] = *(const s16x8*)(Wh0 + (size_t)(gi * 128 + col) * 128 + kk * 32 + kg * 8);
      b0v[gi] = b0[gi * 128 + col];
      c0r[gi] = 0.f;
    }
    const float bov_ = bo[col];
    for (int i = tid; i < 2560; i += 512) xint[i] = 0;
    for (int i = tid; i < 2048; i += 512) htile[i] = 0;
    __syncthreads();

    for (int s = 0; s < 64; ++s) {
      // stage 1: gates0 = W0.xin + Wh0.h0
      s16x8 ax[5], ah[4];
#pragma unroll
      for (int kk = 0; kk < 5; ++kk)
        ax[kk] = *(const s16x8*)((const char*)xint + lr * 320 + kk * 64 + kg * 16);
#pragma unroll
      for (int kk = 0; kk < 4; ++kk)
        ah[kk] = *(const s16x8*)((const char*)htile + lr * 256 + kk * 64 + kg * 16);
      f32x4 acc[4];
#pragma unroll
      for (int gi = 0; gi < 4; ++gi) acc[gi] = (f32x4){b0v[gi], b0v[gi], b0v[gi], b0v[gi]};
#pragma unroll
      for (int kk = 0; kk < 5; ++kk)
#pragma unroll
        for (int gi = 0; gi < 4; ++gi)
          acc[gi] = __builtin_amdgcn_mfma_f32_16x16x32_bf16(ax[kk], wf0[gi][kk], acc[gi], 0, 0, 0);
#pragma unroll
      for (int kk = 0; kk < 4; ++kk)
#pragma unroll
        for (int gi = 0; gi < 4; ++gi)
          acc[gi] = __builtin_amdgcn_mfma_f32_16x16x32_bf16(ah[kk], wfh[gi][kk], acc[gi], 0, 0, 0);
      __syncthreads();
#pragma unroll
      for (int e = 0; e < 4; ++e) {
        const float gi_ = sigf(acc[0][e]), gf = sigf(acc[1][e]);
        const float gg = tanhf_(acc[2][e]), go = sigf(acc[3][e]);
        c0r[e] = gf * c0r[e] + gi_ * gg;
        const float h = go * tanhf_(c0r[e]);
        htile[(rbase + e) * 128 + col] = f2bf(h);
        astoref(&h0g[(size_t)(b016 + rbase + e) * 128 + col], h);
      }
      __syncthreads();
      if (tid == 0) __hip_atomic_fetch_add(cnt_h0 + s, 1u, __ATOMIC_RELEASE, __HIP_MEMORY_SCOPE_AGENT);

      attn_step(s, b, half, tid, l, wv, cnt_q, cnt_cv, qg, ctvg, Kl, Vl, sc, qx, red, mxs, isl);

      // stage D: wait all ctv, then ct = Wo.ctv + bo, y = lin([h1,ct])
      if (tid == 0) {
        while (__hip_atomic_load(cnt_cv + s, __ATOMIC_ACQUIRE, __HIP_MEMORY_SCOPE_AGENT) < 256u)
          __builtin_amdgcn_s_sleep(2);
      }
      __syncthreads();
      for (int i = tid; i < 1024; i += 512)
        ((unsigned long long*)scratch)[i] = aload64((const unsigned long long*)ctvg + (size_t)b016 * 64 + i);
      __syncthreads();
      s16x8 act[4], wof[4];
#pragma unroll
      for (int kk = 0; kk < 4; ++kk) {
        wof[kk] = *(const s16x8*)(Wod + (size_t)col * 128 + kk * 32 + kg * 8);
        s16x8 r;
#pragma unroll
        for (int e = 0; e < 8; ++e) r[e] = (short)f2bf(scratch[lr * 128 + kk * 32 + kg * 8 + e]);
        act[kk] = r;
      }
      f32x4 acd = (f32x4){bov_, bov_, bov_, bov_};
#pragma unroll
      for (int kk = 0; kk < 4; ++kk)
        acd = __builtin_amdgcn_mfma_f32_16x16x32_bf16(act[kk], wof[kk], acd, 0, 0, 0);
      __syncthreads();  // scratch (ctv) reads done
      for (int i = tid; i < 1024; i += 512)
        ((unsigned long long*)scratch)[i] = aload64((const unsigned long long*)h1g + (size_t)b016 * 64 + i);
#pragma unroll
      for (int e = 0; e < 4; ++e) {
        xint[(rbase + e) * 160 + 4 + col] = f2bf(acd[e]);
        scratch2[(rbase + e) * 128 + col] = acd[e];
      }
      __syncthreads();
      {  // y: (bl, o, kc) = (tid>>5, (tid>>3)&3, tid&7); reduce over kc
        const int bl = tid >> 5, o = (tid >> 3) & 3, kc = tid & 7;
        const float* lw = linW + o * 256;
        float part = 0.f;
#pragma unroll
        for (int k2 = 0; k2 < 16; ++k2) {
          const int k = kc * 16 + k2;
          part += scratch[bl * 128 + k] * lw[k] + scratch2[bl * 128 + k] * lw[128 + k];
        }
        part += __shfl_xor(part, 1);
        part += __shfl_xor(part, 2);
        part += __shfl_xor(part, 4);
        if (kc == 0) {
          const float yv = part + linb[o];
          out[((size_t)s * 128 + b016 + bl) * 4 + o] = yv;
          xint[bl * 160 + o] = f2bf(yv);
        }
      }
      __syncthreads();
    }
  } else if (g < 16) {
    // ---- layer1 + Wq owner for b in [(g-8)*16, ...)
    const int b016 = (g - 8) * 16;
    s16x8 wi1f[4][4], wh1f[4][4];
    float b1v[4], c1r[4];
#pragma unroll
    for (int gi = 0; gi < 4; ++gi) {
#pragma unroll
      for (int kk = 0; kk < 4; ++kk) {
        wi1f[gi][kk] = *(const s16x8*)(Wi1 + (size_t)(gi * 128 + col) * 128 + kk * 32 + kg * 8);
        wh1f[gi][kk] = *(const s16x8*)(Wh1 + (size_t)(gi * 128 + col) * 128 + kk * 32 + kg * 8);
      }
      b1v[gi] = b1[gi * 128 + col];
      c1r[gi] = 0.f;
    }
    const float bqv_ = bq[col];
    for (int i = tid; i < 2048; i += 512) htile[i] = 0;
    __syncthreads();

    for (int s = 0; s < 64; ++s) {
      if (tid == 0) {
        while (__hip_atomic_load(cnt_h0 + s, __ATOMIC_ACQUIRE, __HIP_MEMORY_SCOPE_AGENT) < 8u)
          __builtin_amdgcn_s_sleep(2);
      }
      __syncthreads();
      s16x8 ah0[4], ah1[4];
#pragma unroll
      for (int kk = 0; kk < 4; ++kk) {
        const unsigned long long* hp = (const unsigned long long*)(h0g + (size_t)(b016 + lr) * 128 + kk * 32 + kg * 8);
        s16x8 r;
#pragma unroll
        for (int q2 = 0; q2 < 4; ++q2) {
          const unsigned long long u = aload64(hp + q2);
          r[q2 * 2]     = (short)f2bf(__builtin_bit_cast(float, (unsigned)u));
          r[q2 * 2 + 1] = (short)f2bf(__builtin_bit_cast(float, (unsigned)(u >> 32)));
        }
        ah0[kk] = r;
        ah1[kk] = *(const s16x8*)((const char*)htile + lr * 256 + kk * 64 + kg * 16);
      }
      f32x4 acc[4];
#pragma unroll
      for (int gi = 0; gi < 4; ++gi) acc[gi] = (f32x4){b1v[gi], b1v[gi], b1v[gi], b1v[gi]};
#pragma unroll
      for (int kk = 0; kk < 4; ++kk)
#pragma unroll
        for (int gi = 0; gi < 4; ++gi) {
          acc[gi] = __builtin_amdgcn_mfma_f32_16x16x32_bf16(ah0[kk], wi1f[gi][kk], acc[gi], 0, 0, 0);
          acc[gi] = __builtin_amdgcn_mfma_f32_16x16x32_bf16(ah1[kk], wh1f[gi][kk], acc[gi], 0, 0, 0);
        }
      __syncthreads();
#pragma unroll
      for (int e = 0; e < 4; ++e) {
        const float gi_ = sigf(acc[0][e]), gf = sigf(acc[1][e]);
        const float gg = tanhf_(acc[2][e]), go = sigf(acc[3][e]);
        c1r[e] = gf * c1r[e] + gi_ * gg;
        const float h = go * tanhf_(c1r[e]);
        htile[(rbase + e) * 128 + col] = f2bf(h);
        astoref(&h1g[(size_t)(b016 + rbase + e) * 128 + col], h);
      }
      __syncthreads();
      // q = Wq.h1 + bq
      s16x8 aq[4], wqf[4];
#pragma unroll
      for (int kk = 0; kk < 4; ++kk) {
        aq[kk]  = *(const s16x8*)((const char*)htile + lr * 256 + kk * 64 + kg * 16);
        wqf[kk] = *(const s16x8*)(Wqd + (size_t)col * 128 + kk * 32 + kg * 8);
      }
      f32x4 qa = (f32x4){bqv_, bqv_, bqv_, bqv_};
#pragma unroll
      for (int kk = 0; kk < 4; ++kk)
        qa = __builtin_amdgcn_mfma_f32_16x16x32_bf16(aq[kk], wqf[kk], qa, 0, 0, 0);
#pragma unroll
      for (int e = 0; e < 4; ++e)
        astoref(&qg[(size_t)(b016 + rbase + e) * 128 + col], qa[e]);
      __syncthreads();
      if (tid == 0) __hip_atomic_fetch_add(cnt_q + s, 1u, __ATOMIC_RELEASE, __HIP_MEMORY_SCOPE_AGENT);

      attn_step(s, b, half, tid, l, wv, cnt_q, cnt_cv, qg, ctvg, Kl, Vl, sc, qx, red, mxs, isl);
    }
  } else {
    for (int s = 0; s < 64; ++s)
      attn_step(s, b, half, tid, l, wv, cnt_q, cnt_cv, qg, ctvg, Kl, Vl, sc, qx, red, mxs, isl);
  }
}

// ---------------------------------------------------------------- launch
extern "C" void kernel_launch(void* const* d_in, const int* in_sizes, int n_in,
                              void* d_out, int out_size, void* d_ws, size_t ws_size,
                              hipStream_t stream) {
  (void)in_sizes; (void)n_in; (void)out_size; (void)ws_size;
  const float* x     = (const float*)d_in[0];
  const float* eWih0 = (const float*)d_in[1];
  const float* eWhh0 = (const float*)d_in[2];
  const float* eb0   = (const float*)d_in[3];
  const float* eWih1 = (const float*)d_in[4];
  const float* eWhh1 = (const float*)d_in[5];
  const float* eb1   = (const float*)d_in[6];
  const float* dWih0 = (const float*)d_in[7];
  const float* dWhh0 = (const float*)d_in[8];
  const float* db0   = (const float*)d_in[9];
  const float* dWih1 = (const float*)d_in[10];
  const float* dWhh1 = (const float*)d_in[11];
  const float* db1   = (const float*)d_in[12];
  const float* Wq    = (const float*)d_in[13];
  const float* bq    = (const float*)d_in[14];
  const float* Wk    = (const float*)d_in[15];
  const float* bk    = (const float*)d_in[16];
  const float* Wv    = (const float*)d_in[17];
  const float* bv    = (const float*)d_in[18];
  const float* Wo    = (const float*)d_in[19];
  const float* bo    = (const float*)d_in[20];
  const float* linW  = (const float*)d_in[21];
  const float* linb  = (const float*)d_in[22];

  char* w = (char*)d_ws;
  unsigned* cnts = (unsigned*)w;                         // 1024 B (192 used)
  float* qg   = (float*)(w + 1024);                      // 64 KB
  float* h0g  = (float*)(w + 1024 + 65536);              // 64 KB
  float* h1g  = (float*)(w + 1024 + 131072);             // 64 KB
  float* ctvg = (float*)(w + 1024 + 196608);             // 64 KB
  float* pre  = (float*)(w + 524288);                    // 128 MB
  size_t off = 524288 + (size_t)65536 * 512 * 4;
  unsigned short* hs0  = (unsigned short*)(w + off); off += (size_t)65536 * 128 * 2;
  unsigned short* enc  = (unsigned short*)(w + off); off += (size_t)65536 * 128 * 2;
  unsigned short* kbuf = (unsigned short*)(w + off); off += (size_t)65536 * 128 * 2;
  unsigned short* vbuf = (unsigned short*)(w + off); off += (size_t)65536 * 128 * 2;
  unsigned short* W0p  = (unsigned short*)(w + off); off += 512 * 160 * 2;
  unsigned short* Wh0d = (unsigned short*)(w + off); off += 512 * 128 * 2;
  unsigned short* Wi1d = (unsigned short*)(w + off); off += 512 * 128 * 2;
  unsigned short* Wh1d = (unsigned short*)(w + off); off += 512 * 128 * 2;
  unsigned short* Wqd  = (unsigned short*)(w + off); off += 128 * 128 * 2;
  unsigned short* Wod  = (unsigned short*)(w + off); off += 128 * 128 * 2;

  hipMemsetAsync(w, 0, 1024, stream);  // zero flag counters every call

  conv_pad<<<(512 * 160 + 255) / 256, 256, 0, stream>>>(dWih0, W0p, 512, 132, 160);
  conv_pad<<<(512 * 128 + 255) / 256, 256, 0, stream>>>(dWhh0, Wh0d, 512, 128, 128);
  conv_pad<<<(512 * 128 + 255) / 256, 256, 0, stream>>>(dWih1, Wi1d, 512, 128, 128);
  conv_pad<<<(512 * 128 + 255) / 256, 256, 0, stream>>>(dWhh1, Wh1d, 512, 128, 128);
  conv_pad<<<(128 * 128 + 255) / 256, 256, 0, stream>>>(Wq, Wqd, 128, 128, 128);
  conv_pad<<<(128 * 128 + 255) / 256, 256, 0, stream>>>(Wo, Wod, 128, 128, 128);

  // encoder
  gemm_bt<0, 0><<<dim3(4, 512), 256, 0, stream>>>((const void*)x, eWih0, eb0, (void*)pre, 65536, 512, 1024);
  lstm_scan<<<8, 512, 0, stream>>>(pre, eWhh0, hs0, 512);
  gemm_bt<1, 0><<<dim3(4, 512), 256, 0, stream>>>((const void*)hs0, eWih1, eb1, (void*)pre, 65536, 512, 128);
  lstm_scan<<<8, 512, 0, stream>>>(pre, eWhh1, enc, 512);
  // K/V projections
  gemm_bt<1, 1><<<dim3(1, 512), 256, 0, stream>>>((const void*)enc, Wk, bk, (void*)kbuf, 65536, 128, 128);
  gemm_bt<1, 1><<<dim3(1, 512), 256, 0, stream>>>((const void*)enc, Wv, bv, (void*)vbuf, 65536, 128, 128);

  // persistent decoder: 256 WGs = 1/CU (guaranteed co-resident), big dynamic LDS
  hipFuncSetAttribute((const void*)decoder_persist,
                      hipFuncAttributeMaxDynamicSharedMemorySize, DEC_SMEM);
  decoder_persist<<<256, 512, DEC_SMEM, stream>>>(kbuf, vbuf, W0p, Wh0d, Wi1d, Wh1d, Wqd, Wod,
      db0, db1, bq, bo, linW, linb, qg, h0g, h1g, ctvg, cnts, (float*)d_out);
}

// Round 5
// 8587.019 us; speedup vs baseline: 1.5118x; 1.0262x over previous
//
#include <hip/hip_runtime.h>
#include <hip/hip_bf16.h>

typedef __attribute__((ext_vector_type(8))) short s16x8;
typedef __attribute__((ext_vector_type(4))) float f32x4;

__device__ inline unsigned short f2bf(float f) {
  unsigned u = __builtin_bit_cast(unsigned, f);
  unsigned r = (u + 0x7FFFu + ((u >> 16) & 1u)) >> 16;  // RTNE
  return (unsigned short)r;
}
__device__ inline float bf2f(short v) {
  return __builtin_bit_cast(float, ((unsigned)(unsigned short)v) << 16);
}
__device__ inline float sigf(float x) { return 1.f / (1.f + __expf(-x)); }
__device__ inline float tanhf_(float x) { float e = __expf(2.f * x); return 1.f - 2.f / (e + 1.f); }

__device__ inline unsigned long long aload64(const unsigned long long* p) {
  return __hip_atomic_load(p, __ATOMIC_RELAXED, __HIP_MEMORY_SCOPE_AGENT);
}
__device__ inline float aloadf(const float* p) {
  return __hip_atomic_load(p, __ATOMIC_RELAXED, __HIP_MEMORY_SCOPE_AGENT);
}
__device__ inline void astoref(float* p, float v) {
  __hip_atomic_store(p, v, __ATOMIC_RELAXED, __HIP_MEMORY_SCOPE_AGENT);
}
__device__ inline void flag_set(unsigned* p, unsigned v) {
  __hip_atomic_store(p, v, __ATOMIC_RELEASE, __HIP_MEMORY_SCOPE_AGENT);
}
__device__ inline unsigned flag_get(const unsigned* p) {
  return __hip_atomic_load(p, __ATOMIC_ACQUIRE, __HIP_MEMORY_SCOPE_AGENT);
}

// ---------------------------------------------------------------- conv/pad
__global__ void conv_pad(const float* __restrict__ src, unsigned short* __restrict__ dst,
                         int rows, int scols, int dcols) {
  int i = blockIdx.x * 256 + threadIdx.x;
  if (i >= rows * dcols) return;
  int r = i / dcols, cc = i % dcols;
  dst[i] = (cc < scols) ? f2bf(src[(size_t)r * scols + cc]) : (unsigned short)0;
}

// ---------------------------------------------------------------- GEMM C = A @ B^T + bias
#define BM 128
#define BN 128
#define BKK 32

template<int A_BF16, int C_BF16>
__global__ __launch_bounds__(256) void gemm_bt(const void* __restrict__ Av,
    const float* __restrict__ B, const float* __restrict__ bias,
    void* __restrict__ Cv, int M, int N, int K) {
  __shared__ short sA[BM * BKK];
  __shared__ short sB[BN * BKK];
  const int tid = threadIdx.x;
  const int l = tid & 63;
  const int wid = tid >> 6;
  const int wr = wid >> 1, wc = wid & 1;
  const int lr = l & 15, kg = l >> 4;
  const int bn = blockIdx.x, bm = blockIdx.y;
  const int arow = tid >> 1;
  const int acol = (tid & 1) * 16;

  f32x4 acc[4][4];
#pragma unroll
  for (int i = 0; i < 4; ++i)
#pragma unroll
    for (int j = 0; j < 4; ++j) acc[i][j] = (f32x4){0.f, 0.f, 0.f, 0.f};

  for (int kt = 0; kt < K; kt += BKK) {
    __syncthreads();
    if (A_BF16) {
      const unsigned short* src = (const unsigned short*)Av + (size_t)(bm * BM + arow) * K + kt + acol;
      *(s16x8*)&sA[arow * BKK + acol] = *(const s16x8*)src;
      *(s16x8*)&sA[arow * BKK + acol + 8] = *(const s16x8*)(src + 8);
    } else {
      const float* src = (const float*)Av + (size_t)(bm * BM + arow) * K + kt + acol;
      s16x8 v0, v1;
#pragma unroll
      for (int e = 0; e < 8; ++e) { v0[e] = (short)f2bf(src[e]); v1[e] = (short)f2bf(src[8 + e]); }
      *(s16x8*)&sA[arow * BKK + acol] = v0;
      *(s16x8*)&sA[arow * BKK + acol + 8] = v1;
    }
    {
      const float* src = B + (size_t)(bn * BN + arow) * K + kt + acol;
      s16x8 v0, v1;
#pragma unroll
      for (int e = 0; e < 8; ++e) { v0[e] = (short)f2bf(src[e]); v1[e] = (short)f2bf(src[8 + e]); }
      *(s16x8*)&sB[arow * BKK + acol] = v0;
      *(s16x8*)&sB[arow * BKK + acol + 8] = v1;
    }
    __syncthreads();
    s16x8 af[4], bfr[4];
#pragma unroll
    for (int mi = 0; mi < 4; ++mi)
      af[mi] = *(const s16x8*)&sA[(wr * 64 + mi * 16 + lr) * BKK + kg * 8];
#pragma unroll
    for (int ni = 0; ni < 4; ++ni)
      bfr[ni] = *(const s16x8*)&sB[(wc * 64 + ni * 16 + lr) * BKK + kg * 8];
#pragma unroll
    for (int mi = 0; mi < 4; ++mi)
#pragma unroll
      for (int ni = 0; ni < 4; ++ni)
        acc[mi][ni] = __builtin_amdgcn_mfma_f32_16x16x32_bf16(af[mi], bfr[ni], acc[mi][ni], 0, 0, 0);
  }
  const int r0 = bm * BM + wr * 64;
  const int c0 = bn * BN + wc * 64;
#pragma unroll
  for (int mi = 0; mi < 4; ++mi)
#pragma unroll
    for (int ni = 0; ni < 4; ++ni) {
      const int col = c0 + ni * 16 + lr;
      const float bv = bias[col];
#pragma unroll
      for (int e = 0; e < 4; ++e) {
        const int row = r0 + mi * 16 + kg * 4 + e;
        const float v = acc[mi][ni][e] + bv;
        if (C_BF16) ((unsigned short*)Cv)[(size_t)row * N + col] = f2bf(v);
        else        ((float*)Cv)[(size_t)row * N + col] = v;
      }
    }
}

// ---------------------------------------------------------------- encoder LSTM scan
__global__ __launch_bounds__(512) void lstm_scan(const float* __restrict__ pre,
    const float* __restrict__ Whh, unsigned short* __restrict__ hs, int T) {
  __shared__ unsigned short hb[2][2048];
  const int tid = threadIdx.x;
  const int l = tid & 63, w = tid >> 6;
  const int wg = blockIdx.x;
  const int lr = l & 15, kg = l >> 4;
  const int col = w * 16 + lr;
  const int rbase = kg * 4;

  s16x8 wf[4][4];
#pragma unroll
  for (int gi = 0; gi < 4; ++gi)
#pragma unroll
    for (int kk = 0; kk < 4; ++kk) {
      const float* p = Whh + (size_t)(gi * 128 + col) * 128 + kk * 32 + kg * 8;
#pragma unroll
      for (int e = 0; e < 8; ++e) wf[gi][kk][e] = (short)f2bf(p[e]);
    }
  for (int i = tid; i < 4096; i += 512) ((unsigned short*)hb)[i] = 0;
  float c[4] = {0.f, 0.f, 0.f, 0.f};

  const float* pbase = pre + ((size_t)(wg * 16 + rbase)) * 512 + col;
  float pf[16];
#pragma unroll
  for (int gi = 0; gi < 4; ++gi)
#pragma unroll
    for (int e = 0; e < 4; ++e) pf[gi * 4 + e] = pbase[e * 512 + gi * 128];
  __syncthreads();

  for (int t = 0; t < T; ++t) {
    const unsigned short* hc = hb[t & 1];
    unsigned short* hn = hb[(t & 1) ^ 1];
    s16x8 a[4];
#pragma unroll
    for (int kk = 0; kk < 4; ++kk) {
      const int byt = lr * 256 + ((kk * 64 + kg * 16) ^ ((lr & 7) << 4));
      a[kk] = *(const s16x8*)((const char*)hc + byt);
    }
    f32x4 acc[4];
#pragma unroll
    for (int gi = 0; gi < 4; ++gi)
      acc[gi] = (f32x4){pf[gi * 4], pf[gi * 4 + 1], pf[gi * 4 + 2], pf[gi * 4 + 3]};
    float pfn[16];
    if (t + 1 < T) {
      const float* pb2 = pbase + (size_t)(t + 1) * 65536;
#pragma unroll
      for (int gi = 0; gi < 4; ++gi)
#pragma unroll
        for (int e = 0; e < 4; ++e) pfn[gi * 4 + e] = pb2[e * 512 + gi * 128];
    } else {
#pragma unroll
      for (int i2 = 0; i2 < 16; ++i2) pfn[i2] = 0.f;
    }
#pragma unroll
    for (int kk = 0; kk < 4; ++kk)
#pragma unroll
      for (int gi = 0; gi < 4; ++gi)
        acc[gi] = __builtin_amdgcn_mfma_f32_16x16x32_bf16(a[kk], wf[gi][kk], acc[gi], 0, 0, 0);
#pragma unroll
    for (int e = 0; e < 4; ++e) {
      float gi_ = sigf(acc[0][e]);
      float gf  = sigf(acc[1][e]);
      float gg  = tanhf_(acc[2][e]);
      float go  = sigf(acc[3][e]);
      c[e] = gf * c[e] + gi_ * gg;
      float h = go * tanhf_(c[e]);
      unsigned short hu = f2bf(h);
      int row = rbase + e;
      int byt = row * 256 + ((col * 2) ^ ((row & 7) << 4));
      *(unsigned short*)((char*)hn + byt) = hu;
      hs[((size_t)t * 128 + wg * 16 + row) * 128 + col] = hu;
    }
#pragma unroll
    for (int i2 = 0; i2 < 16; ++i2) pf[i2] = pfn[i2];
    __syncthreads();
  }
}

// ---------------------------------------------------------------- persistent decoder
// 256 WGs (1/CU). WG g: b=g>>1, half=g&1 holds K/V[b, heads half*2..half*2+1] in LDS.
// WGs 0-7: layer0 + Wo/lin (16 b each). WGs 8-15: layer1 + Wq.
// Sync: single-writer release flags (value = step+1), 64B-strided:
//   fA[i]  stage1 WG i  -> stage2 WG 8+i          (1 poller)
//   fQ[b]  stage2 group -> attn WGs 2b, 2b+1      (2 pollers)
//   fC[g]  attn WG g    -> stageD owner WG b>>4   (1 poller lane)

__device__ __forceinline__ void attn_step(
    int s, int b, int half, int tid, int l, int wv,
    const unsigned* fQb, unsigned* fCg,
    const float* qg, float* ctvg,
    const unsigned short* Kl, const unsigned short* Vl,
    float* sc, float* qx, float* red, float* mxs, float* isl)
{
  if (tid == 0) {
    while (flag_get(fQb) <= (unsigned)s) __builtin_amdgcn_s_sleep(1);
  }
  __syncthreads();
  if (tid < 64) qx[tid] = aloadf(&qg[(size_t)b * 128 + half * 64 + tid]);
  __syncthreads();
  const int t = tid;
  float s2[2] = {0.f, 0.f};
#pragma unroll
  for (int c = 0; c < 8; ++c) {
    const s16x8 kv = *(const s16x8*)((const char*)Kl + t * 128 + (((c + t) & 7) << 4));
    float d = 0.f;
#pragma unroll
    for (int e = 0; e < 8; ++e) d += qx[c * 8 + e] * bf2f(kv[e]);
    s2[c >> 2] += d;
  }
  const float scale = 0.1767766952966369f;  // 1/sqrt(32)
  s2[0] *= scale; s2[1] *= scale;
#pragma unroll
  for (int hh = 0; hh < 2; ++hh) {
    float m = s2[hh];
#pragma unroll
    for (int off = 32; off > 0; off >>= 1) m = fmaxf(m, __shfl_xor(m, off));
    if (l == 0) red[hh * 8 + wv] = m;
  }
  __syncthreads();
  if (tid < 2) {
    float m = red[tid * 8];
#pragma unroll
    for (int w2 = 1; w2 < 8; ++w2) m = fmaxf(m, red[tid * 8 + w2]);
    mxs[tid] = m;
  }
  __syncthreads();
#pragma unroll
  for (int hh = 0; hh < 2; ++hh) {
    float p = __expf(s2[hh] - mxs[hh]);
    sc[hh * 512 + t] = p;
    float ps = p;
#pragma unroll
    for (int off = 32; off > 0; off >>= 1) ps += __shfl_xor(ps, off);
    if (l == 0) red[16 + hh * 8 + wv] = ps;
  }
  __syncthreads();
  if (tid < 2) {
    float sm = red[16 + tid * 8];
#pragma unroll
    for (int w2 = 1; w2 < 8; ++w2) sm += red[16 + tid * 8 + w2];
    isl[tid] = 1.f / sm;
  }
  __syncthreads();
  {
    const int hh = tid >> 8, dg = (tid >> 6) & 3, tc = tid & 63;
    const int c = hh * 4 + dg;
    float a8[8] = {0.f, 0.f, 0.f, 0.f, 0.f, 0.f, 0.f, 0.f};
#pragma unroll
    for (int tt = 0; tt < 8; ++tt) {
      const int tr = tc * 8 + ((tt + tc) & 7);
      const s16x8 vv = *(const s16x8*)((const char*)Vl + tr * 128 + (((c + tr) & 7) << 4));
      const float p = sc[hh * 512 + tr];
#pragma unroll
      for (int e = 0; e < 8; ++e) a8[e] += p * bf2f(vv[e]);
    }
#pragma unroll
    for (int off = 32; off > 0; off >>= 1)
#pragma unroll
      for (int e = 0; e < 8; ++e) a8[e] += __shfl_xor(a8[e], off);
    if (tc == 0) {
      const float iv = isl[hh];
#pragma unroll
      for (int e = 0; e < 8; ++e)
        astoref(&ctvg[(size_t)b * 128 + half * 64 + c * 8 + e], a8[e] * iv);
    }
  }
  __syncthreads();
  if (tid == 0) flag_set(fCg, (unsigned)(s + 1));
}

#define DEC_SMEM 161280

__global__ void __launch_bounds__(512, 2) decoder_persist(
    const unsigned short* __restrict__ kb, const unsigned short* __restrict__ vb,
    const unsigned short* __restrict__ W0p, const unsigned short* __restrict__ Wh0,
    const unsigned short* __restrict__ Wi1, const unsigned short* __restrict__ Wh1,
    const unsigned short* __restrict__ Wqd, const unsigned short* __restrict__ Wod,
    const float* __restrict__ b0, const float* __restrict__ b1,
    const float* __restrict__ bq, const float* __restrict__ bo,
    const float* __restrict__ linW, const float* __restrict__ linb,
    float* __restrict__ qg, float* __restrict__ h0g, float* __restrict__ h1g,
    float* __restrict__ ctvg, unsigned* __restrict__ flags, float* __restrict__ out)
{
  extern __shared__ char smem[];
  unsigned short* Kl = (unsigned short*)smem;              // [512][64] skewed
  unsigned short* Vl = (unsigned short*)(smem + 65536);    // [512][64] skewed
  float* sc   = (float*)(smem + 131072);                   // [2][512]
  float* qx   = (float*)(smem + 135168);                   // [64]
  float* red  = (float*)(smem + 135424);                   // [32]
  float* mxs  = (float*)(smem + 135552);                   // [2]
  float* isl  = (float*)(smem + 135560);                   // [2]
  unsigned short* xint  = (unsigned short*)(smem + 135680);// [16][160] linear
  unsigned short* htile = (unsigned short*)(smem + 140800);// [16][128] linear
  float* scratch  = (float*)(smem + 144896);               // [2048]
  float* scratch2 = (float*)(smem + 153088);               // [2048]

  const int g = blockIdx.x;
  const int tid = threadIdx.x;
  const int b = g >> 1, half = g & 1;
  const int l = tid & 63, wv = tid >> 6;
  const int lr = l & 15, kg = l >> 4;
  const int col = wv * 16 + lr;
  const int rbase = kg * 4;
  unsigned* fA = flags;            // 8 flags, stride 16 u32
  unsigned* fQ = flags + 256;      // 128 flags, stride 16 u32
  unsigned* fC = flags + 4096;     // 256 flags, stride 16 u32
  const unsigned* fQb = fQ + (size_t)b * 16;
  unsigned* fCg = fC + (size_t)g * 16;

  // one-time K/V load into LDS (row t: 8 16B octets, skew slot=(c+t)&7)
  {
    const int t = tid;
    const unsigned short* krow = kb + ((size_t)t * 128 + b) * 128 + half * 64;
    const unsigned short* vrow = vb + ((size_t)t * 128 + b) * 128 + half * 64;
#pragma unroll
    for (int c = 0; c < 8; ++c) {
      const s16x8 kv = *(const s16x8*)(krow + c * 8);
      const s16x8 vv = *(const s16x8*)(vrow + c * 8);
      const int sl = ((c + t) & 7) << 4;
      *(s16x8*)((char*)Kl + t * 128 + sl) = kv;
      *(s16x8*)((char*)Vl + t * 128 + sl) = vv;
    }
  }

  if (g < 8) {
    // ---- layer0 + Wo + lin owner for b in [g*16, g*16+16)
    const int b016 = g * 16;
    s16x8 wf0[4][5], wfh[4][4];
    float b0v[4], c0r[4];
#pragma unroll
    for (int gi = 0; gi < 4; ++gi) {
#pragma unroll
      for (int kk = 0; kk < 5; ++kk)
        wf0[gi][kk] = *(const s16x8*)(W0p + (size_t)(gi * 128 + col) * 160 + kk * 32 + kg * 8);
#pragma unroll
      for (int kk = 0; kk < 4; ++kk)
        wfh[gi][kk] = *(const s16x8*)(Wh0 + (size_t)(gi * 128 + col) * 128 + kk * 32 + kg * 8);
      b0v[gi] = b0[gi * 128 + col];
      c0r[gi] = 0.f;
    }
    const float bov_ = bo[col];
    for (int i = tid; i < 2560; i += 512) xint[i] = 0;
    for (int i = tid; i < 2048; i += 512) htile[i] = 0;
    __syncthreads();

    for (int s = 0; s < 64; ++s) {
      // stage 1: gates0 = W0.xin + Wh0.h0
      s16x8 ax[5], ah[4];
#pragma unroll
      for (int kk = 0; kk < 5; ++kk)
        ax[kk] = *(const s16x8*)((const char*)xint + lr * 320 + kk * 64 + kg * 16);
#pragma unroll
      for (int kk = 0; kk < 4; ++kk)
        ah[kk] = *(const s16x8*)((const char*)htile + lr * 256 + kk * 64 + kg * 16);
      f32x4 acc[4];
#pragma unroll
      for (int gi = 0; gi < 4; ++gi) acc[gi] = (f32x4){b0v[gi], b0v[gi], b0v[gi], b0v[gi]};
#pragma unroll
      for (int kk = 0; kk < 5; ++kk)
#pragma unroll
        for (int gi = 0; gi < 4; ++gi)
          acc[gi] = __builtin_amdgcn_mfma_f32_16x16x32_bf16(ax[kk], wf0[gi][kk], acc[gi], 0, 0, 0);
#pragma unroll
      for (int kk = 0; kk < 4; ++kk)
#pragma unroll
        for (int gi = 0; gi < 4; ++gi)
          acc[gi] = __builtin_amdgcn_mfma_f32_16x16x32_bf16(ah[kk], wfh[gi][kk], acc[gi], 0, 0, 0);
      __syncthreads();
#pragma unroll
      for (int e = 0; e < 4; ++e) {
        const float gi_ = sigf(acc[0][e]), gf = sigf(acc[1][e]);
        const float gg = tanhf_(acc[2][e]), go = sigf(acc[3][e]);
        c0r[e] = gf * c0r[e] + gi_ * gg;
        const float h = go * tanhf_(c0r[e]);
        htile[(rbase + e) * 128 + col] = f2bf(h);
        astoref(&h0g[(size_t)(b016 + rbase + e) * 128 + col], h);
      }
      __syncthreads();
      if (tid == 0) flag_set(fA + g * 16, (unsigned)(s + 1));

      attn_step(s, b, half, tid, l, wv, fQb, fCg, qg, ctvg, Kl, Vl, sc, qx, red, mxs, isl);

      // stage D: wait for all 32 ctv producers of this b-group (one flag per lane)
      if (tid < 32) {
        const unsigned* fp = fC + (size_t)(g * 32 + tid) * 16;
        while (flag_get(fp) <= (unsigned)s) __builtin_amdgcn_s_sleep(1);
      }
      __syncthreads();
      for (int i = tid; i < 1024; i += 512)
        ((unsigned long long*)scratch)[i] = aload64((const unsigned long long*)ctvg + (size_t)b016 * 64 + i);
      __syncthreads();
      s16x8 act[4], wof[4];
#pragma unroll
      for (int kk = 0; kk < 4; ++kk) {
        wof[kk] = *(const s16x8*)(Wod + (size_t)col * 128 + kk * 32 + kg * 8);
        s16x8 r;
#pragma unroll
        for (int e = 0; e < 8; ++e) r[e] = (short)f2bf(scratch[lr * 128 + kk * 32 + kg * 8 + e]);
        act[kk] = r;
      }
      f32x4 acd = (f32x4){bov_, bov_, bov_, bov_};
#pragma unroll
      for (int kk = 0; kk < 4; ++kk)
        acd = __builtin_amdgcn_mfma_f32_16x16x32_bf16(act[kk], wof[kk], acd, 0, 0, 0);
      __syncthreads();  // scratch (ctv) reads done
      for (int i = tid; i < 1024; i += 512)
        ((unsigned long long*)scratch)[i] = aload64((const unsigned long long*)h1g + (size_t)b016 * 64 + i);
#pragma unroll
      for (int e = 0; e < 4; ++e) {
        xint[(rbase + e) * 160 + 4 + col] = f2bf(acd[e]);
        scratch2[(rbase + e) * 128 + col] = acd[e];
      }
      __syncthreads();
      {  // y: (bl, o, kc) = (tid>>5, (tid>>3)&3, tid&7); reduce over kc
        const int bl = tid >> 5, o = (tid >> 3) & 3, kc = tid & 7;
        const float* lw = linW + o * 256;
        float part = 0.f;
#pragma unroll
        for (int k2 = 0; k2 < 16; ++k2) {
          const int k = kc * 16 + k2;
          part += scratch[bl * 128 + k] * lw[k] + scratch2[bl * 128 + k] * lw[128 + k];
        }
        part += __shfl_xor(part, 1);
        part += __shfl_xor(part, 2);
        part += __shfl_xor(part, 4);
        if (kc == 0) {
          const float yv = part + linb[o];
          out[((size_t)s * 128 + b016 + bl) * 4 + o] = yv;
          xint[bl * 160 + o] = f2bf(yv);
        }
      }
      __syncthreads();
    }
  } else if (g < 16) {
    // ---- layer1 + Wq owner for b in [(g-8)*16, ...)
    const int grp = g - 8;
    const int b016 = grp * 16;
    s16x8 wi1f[4][4], wh1f[4][4];
    float b1v[4], c1r[4];
#pragma unroll
    for (int gi = 0; gi < 4; ++gi) {
#pragma unroll
      for (int kk = 0; kk < 4; ++kk) {
        wi1f[gi][kk] = *(const s16x8*)(Wi1 + (size_t)(gi * 128 + col) * 128 + kk * 32 + kg * 8);
        wh1f[gi][kk] = *(const s16x8*)(Wh1 + (size_t)(gi * 128 + col) * 128 + kk * 32 + kg * 8);
      }
      b1v[gi] = b1[gi * 128 + col];
      c1r[gi] = 0.f;
    }
    const float bqv_ = bq[col];
    for (int i = tid; i < 2048; i += 512) htile[i] = 0;
    __syncthreads();

    for (int s = 0; s < 64; ++s) {
      if (tid == 0) {
        while (flag_get(fA + grp * 16) <= (unsigned)s) __builtin_amdgcn_s_sleep(1);
      }
      __syncthreads();
      s16x8 ah0[4], ah1[4];
#pragma unroll
      for (int kk = 0; kk < 4; ++kk) {
        const unsigned long long* hp = (const unsigned long long*)(h0g + (size_t)(b016 + lr) * 128 + kk * 32 + kg * 8);
        s16x8 r;
#pragma unroll
        for (int q2 = 0; q2 < 4; ++q2) {
          const unsigned long long u = aload64(hp + q2);
          r[q2 * 2]     = (short)f2bf(__builtin_bit_cast(float, (unsigned)u));
          r[q2 * 2 + 1] = (short)f2bf(__builtin_bit_cast(float, (unsigned)(u >> 32)));
        }
        ah0[kk] = r;
        ah1[kk] = *(const s16x8*)((const char*)htile + lr * 256 + kk * 64 + kg * 16);
      }
      f32x4 acc[4];
#pragma unroll
      for (int gi = 0; gi < 4; ++gi) acc[gi] = (f32x4){b1v[gi], b1v[gi], b1v[gi], b1v[gi]};
#pragma unroll
      for (int kk = 0; kk < 4; ++kk)
#pragma unroll
        for (int gi = 0; gi < 4; ++gi) {
          acc[gi] = __builtin_amdgcn_mfma_f32_16x16x32_bf16(ah0[kk], wi1f[gi][kk], acc[gi], 0, 0, 0);
          acc[gi] = __builtin_amdgcn_mfma_f32_16x16x32_bf16(ah1[kk], wh1f[gi][kk], acc[gi], 0, 0, 0);
        }
      __syncthreads();
#pragma unroll
      for (int e = 0; e < 4; ++e) {
        const float gi_ = sigf(acc[0][e]), gf = sigf(acc[1][e]);
        const float gg = tanhf_(acc[2][e]), go = sigf(acc[3][e]);
        c1r[e] = gf * c1r[e] + gi_ * gg;
        const float h = go * tanhf_(c1r[e]);
        htile[(rbase + e) * 128 + col] = f2bf(h);
        astoref(&h1g[(size_t)(b016 + rbase + e) * 128 + col], h);
      }
      __syncthreads();
      // q = Wq.h1 + bq
      s16x8 aq[4], wqf[4];
#pragma unroll
      for (int kk = 0; kk < 4; ++kk) {
        aq[kk]  = *(const s16x8*)((const char*)htile + lr * 256 + kk * 64 + kg * 16);
        wqf[kk] = *(const s16x8*)(Wqd + (size_t)col * 128 + kk * 32 + kg * 8);
      }
      f32x4 qa = (f32x4){bqv_, bqv_, bqv_, bqv_};
#pragma unroll
      for (int kk = 0; kk < 4; ++kk)
        qa = __builtin_amdgcn_mfma_f32_16x16x32_bf16(aq[kk], wqf[kk], qa, 0, 0, 0);
#pragma unroll
      for (int e = 0; e < 4; ++e)
        astoref(&qg[(size_t)(b016 + rbase + e) * 128 + col], qa[e]);
      __syncthreads();
      if (tid < 16) flag_set(fQ + (size_t)(b016 + tid) * 16, (unsigned)(s + 1));

      attn_step(s, b, half, tid, l, wv, fQb, fCg, qg, ctvg, Kl, Vl, sc, qx, red, mxs, isl);
    }
  } else {
    for (int s = 0; s < 64; ++s)
      attn_step(s, b, half, tid, l, wv, fQb, fCg, qg, ctvg, Kl, Vl, sc, qx, red, mxs, isl);
  }
}

// ---------------------------------------------------------------- launch
extern "C" void kernel_launch(void* const* d_in, const int* in_sizes, int n_in,
                              void* d_out, int out_size, void* d_ws, size_t ws_size,
                              hipStream_t stream) {
  (void)in_sizes; (void)n_in; (void)out_size; (void)ws_size;
  const float* x     = (const float*)d_in[0];
  const float* eWih0 = (const float*)d_in[1];
  const float* eWhh0 = (const float*)d_in[2];
  const float* eb0   = (const float*)d_in[3];
  const float* eWih1 = (const float*)d_in[4];
  const float* eWhh1 = (const float*)d_in[5];
  const float* eb1   = (const float*)d_in[6];
  const float* dWih0 = (const float*)d_in[7];
  const float* dWhh0 = (const float*)d_in[8];
  const float* db0   = (const float*)d_in[9];
  const float* dWih1 = (const float*)d_in[10];
  const float* dWhh1 = (const float*)d_in[11];
  const float* db1   = (const float*)d_in[12];
  const float* Wq    = (const float*)d_in[13];
  const float* bq    = (const float*)d_in[14];
  const float* Wk    = (const float*)d_in[15];
  const float* bk    = (const float*)d_in[16];
  const float* Wv    = (const float*)d_in[17];
  const float* bv    = (const float*)d_in[18];
  const float* Wo    = (const float*)d_in[19];
  const float* bo    = (const float*)d_in[20];
  const float* linW  = (const float*)d_in[21];
  const float* linb  = (const float*)d_in[22];

  char* w = (char*)d_ws;
  unsigned* flags = (unsigned*)w;                        // 32 KB flag region (64B-strided)
  float* qg   = (float*)(w + 65536);                     // 64 KB
  float* h0g  = (float*)(w + 131072);                    // 64 KB
  float* h1g  = (float*)(w + 196608);                    // 64 KB
  float* ctvg = (float*)(w + 262144);                    // 64 KB
  float* pre  = (float*)(w + 524288);                    // 128 MB
  size_t off = 524288 + (size_t)65536 * 512 * 4;
  unsigned short* hs0  = (unsigned short*)(w + off); off += (size_t)65536 * 128 * 2;
  unsigned short* enc  = (unsigned short*)(w + off); off += (size_t)65536 * 128 * 2;
  unsigned short* kbuf = (unsigned short*)(w + off); off += (size_t)65536 * 128 * 2;
  unsigned short* vbuf = (unsigned short*)(w + off); off += (size_t)65536 * 128 * 2;
  unsigned short* W0p  = (unsigned short*)(w + off); off += 512 * 160 * 2;
  unsigned short* Wh0d = (unsigned short*)(w + off); off += 512 * 128 * 2;
  unsigned short* Wi1d = (unsigned short*)(w + off); off += 512 * 128 * 2;
  unsigned short* Wh1d = (unsigned short*)(w + off); off += 512 * 128 * 2;
  unsigned short* Wqd  = (unsigned short*)(w + off); off += 128 * 128 * 2;
  unsigned short* Wod  = (unsigned short*)(w + off); off += 128 * 128 * 2;

  hipMemsetAsync(w, 0, 32768, stream);  // zero flags every call

  conv_pad<<<(512 * 160 + 255) / 256, 256, 0, stream>>>(dWih0, W0p, 512, 132, 160);
  conv_pad<<<(512 * 128 + 255) / 256, 256, 0, stream>>>(dWhh0, Wh0d, 512, 128, 128);
  conv_pad<<<(512 * 128 + 255) / 256, 256, 0, stream>>>(dWih1, Wi1d, 512, 128, 128);
  conv_pad<<<(512 * 128 + 255) / 256, 256, 0, stream>>>(dWhh1, Wh1d, 512, 128, 128);
  conv_pad<<<(128 * 128 + 255) / 256, 256, 0, stream>>>(Wq, Wqd, 128, 128, 128);
  conv_pad<<<(128 * 128 + 255) / 256, 256, 0, stream>>>(Wo, Wod, 128, 128, 128);

  // encoder
  gemm_bt<0, 0><<<dim3(4, 512), 256, 0, stream>>>((const void*)x, eWih0, eb0, (void*)pre, 65536, 512, 1024);
  lstm_scan<<<8, 512, 0, stream>>>(pre, eWhh0, hs0, 512);
  gemm_bt<1, 0><<<dim3(4, 512), 256, 0, stream>>>((const void*)hs0, eWih1, eb1, (void*)pre, 65536, 512, 128);
  lstm_scan<<<8, 512, 0, stream>>>(pre, eWhh1, enc, 512);
  // K/V projections
  gemm_bt<1, 1><<<dim3(1, 512), 256, 0, stream>>>((const void*)enc, Wk, bk, (void*)kbuf, 65536, 128, 128);
  gemm_bt<1, 1><<<dim3(1, 512), 256, 0, stream>>>((const void*)enc, Wv, bv, (void*)vbuf, 65536, 128, 128);

  // persistent decoder: 256 WGs = 1/CU, big dynamic LDS
  hipFuncSetAttribute((const void*)decoder_persist,
                      hipFuncAttributeMaxDynamicSharedMemorySize, DEC_SMEM);
  decoder_persist<<<256, 512, DEC_SMEM, stream>>>(kbuf, vbuf, W0p, Wh0d, Wi1d, Wh1d, Wqd, Wod,
      db0, db1, bq, bo, linW, linb, qg, h0g, h1g, ctvg, flags, (float*)d_out);
}

// Round 6
// 4160.751 us; speedup vs baseline: 3.1201x; 2.0638x over previous
//
#include <hip/hip_runtime.h>
#include <hip/hip_bf16.h>

typedef __attribute__((ext_vector_type(8))) short s16x8;
typedef __attribute__((ext_vector_type(4))) float f32x4;

__device__ inline unsigned short f2bf(float f) {
  unsigned u = __builtin_bit_cast(unsigned, f);
  unsigned r = (u + 0x7FFFu + ((u >> 16) & 1u)) >> 16;  // RTNE
  return (unsigned short)r;
}
__device__ inline float bf2f(short v) {
  return __builtin_bit_cast(float, ((unsigned)(unsigned short)v) << 16);
}
__device__ inline float sigf(float x) { return 1.f / (1.f + __expf(-x)); }
__device__ inline float tanhf_(float x) { float e = __expf(2.f * x); return 1.f - 2.f / (e + 1.f); }

__device__ inline unsigned long long aload64(const unsigned long long* p) {
  return __hip_atomic_load(p, __ATOMIC_RELAXED, __HIP_MEMORY_SCOPE_AGENT);
}
__device__ inline float aloadf(const float* p) {
  return __hip_atomic_load(p, __ATOMIC_RELAXED, __HIP_MEMORY_SCOPE_AGENT);
}
__device__ inline void astoref(float* p, float v) {
  __hip_atomic_store(p, v, __ATOMIC_RELAXED, __HIP_MEMORY_SCOPE_AGENT);
}
__device__ inline void flag_set(unsigned* p, unsigned v) {
  __hip_atomic_store(p, v, __ATOMIC_RELEASE, __HIP_MEMORY_SCOPE_AGENT);
}
// RELAXED spin (no per-iteration buffer_inv), ONE acquire fence on exit.
__device__ inline void wait_flag(const unsigned* p, unsigned s) {
  while (__hip_atomic_load(p, __ATOMIC_RELAXED, __HIP_MEMORY_SCOPE_AGENT) <= s) {}
  __builtin_amdgcn_fence(__ATOMIC_ACQUIRE, "agent");
}

// ---------------------------------------------------------------- conv/pad
__global__ void conv_pad(const float* __restrict__ src, unsigned short* __restrict__ dst,
                         int rows, int scols, int dcols) {
  int i = blockIdx.x * 256 + threadIdx.x;
  if (i >= rows * dcols) return;
  int r = i / dcols, cc = i % dcols;
  dst[i] = (cc < scols) ? f2bf(src[(size_t)r * scols + cc]) : (unsigned short)0;
}

// ---------------------------------------------------------------- GEMM C = A @ B^T + bias
#define BM 128
#define BN 128
#define BKK 32

template<int A_BF16, int C_BF16>
__global__ __launch_bounds__(256) void gemm_bt(const void* __restrict__ Av,
    const float* __restrict__ B, const float* __restrict__ bias,
    void* __restrict__ Cv, int M, int N, int K) {
  __shared__ short sA[BM * BKK];
  __shared__ short sB[BN * BKK];
  const int tid = threadIdx.x;
  const int l = tid & 63;
  const int wid = tid >> 6;
  const int wr = wid >> 1, wc = wid & 1;
  const int lr = l & 15, kg = l >> 4;
  const int bn = blockIdx.x, bm = blockIdx.y;
  const int arow = tid >> 1;
  const int acol = (tid & 1) * 16;

  f32x4 acc[4][4];
#pragma unroll
  for (int i = 0; i < 4; ++i)
#pragma unroll
    for (int j = 0; j < 4; ++j) acc[i][j] = (f32x4){0.f, 0.f, 0.f, 0.f};

  for (int kt = 0; kt < K; kt += BKK) {
    __syncthreads();
    if (A_BF16) {
      const unsigned short* src = (const unsigned short*)Av + (size_t)(bm * BM + arow) * K + kt + acol;
      *(s16x8*)&sA[arow * BKK + acol] = *(const s16x8*)src;
      *(s16x8*)&sA[arow * BKK + acol + 8] = *(const s16x8*)(src + 8);
    } else {
      const float* src = (const float*)Av + (size_t)(bm * BM + arow) * K + kt + acol;
      s16x8 v0, v1;
#pragma unroll
      for (int e = 0; e < 8; ++e) { v0[e] = (short)f2bf(src[e]); v1[e] = (short)f2bf(src[8 + e]); }
      *(s16x8*)&sA[arow * BKK + acol] = v0;
      *(s16x8*)&sA[arow * BKK + acol + 8] = v1;
    }
    {
      const float* src = B + (size_t)(bn * BN + arow) * K + kt + acol;
      s16x8 v0, v1;
#pragma unroll
      for (int e = 0; e < 8; ++e) { v0[e] = (short)f2bf(src[e]); v1[e] = (short)f2bf(src[8 + e]); }
      *(s16x8*)&sB[arow * BKK + acol] = v0;
      *(s16x8*)&sB[arow * BKK + acol + 8] = v1;
    }
    __syncthreads();
    s16x8 af[4], bfr[4];
#pragma unroll
    for (int mi = 0; mi < 4; ++mi)
      af[mi] = *(const s16x8*)&sA[(wr * 64 + mi * 16 + lr) * BKK + kg * 8];
#pragma unroll
    for (int ni = 0; ni < 4; ++ni)
      bfr[ni] = *(const s16x8*)&sB[(wc * 64 + ni * 16 + lr) * BKK + kg * 8];
#pragma unroll
    for (int mi = 0; mi < 4; ++mi)
#pragma unroll
      for (int ni = 0; ni < 4; ++ni)
        acc[mi][ni] = __builtin_amdgcn_mfma_f32_16x16x32_bf16(af[mi], bfr[ni], acc[mi][ni], 0, 0, 0);
  }
  const int r0 = bm * BM + wr * 64;
  const int c0 = bn * BN + wc * 64;
#pragma unroll
  for (int mi = 0; mi < 4; ++mi)
#pragma unroll
    for (int ni = 0; ni < 4; ++ni) {
      const int col = c0 + ni * 16 + lr;
      const float bv = bias[col];
#pragma unroll
      for (int e = 0; e < 4; ++e) {
        const int row = r0 + mi * 16 + kg * 4 + e;
        const float v = acc[mi][ni][e] + bv;
        if (C_BF16) ((unsigned short*)Cv)[(size_t)row * N + col] = f2bf(v);
        else        ((float*)Cv)[(size_t)row * N + col] = v;
      }
    }
}

// ---------------------------------------------------------------- encoder LSTM scan
__global__ __launch_bounds__(512) void lstm_scan(const float* __restrict__ pre,
    const float* __restrict__ Whh, unsigned short* __restrict__ hs, int T) {
  __shared__ unsigned short hb[2][2048];
  const int tid = threadIdx.x;
  const int l = tid & 63, w = tid >> 6;
  const int wg = blockIdx.x;
  const int lr = l & 15, kg = l >> 4;
  const int col = w * 16 + lr;
  const int rbase = kg * 4;

  s16x8 wf[4][4];
#pragma unroll
  for (int gi = 0; gi < 4; ++gi)
#pragma unroll
    for (int kk = 0; kk < 4; ++kk) {
      const float* p = Whh + (size_t)(gi * 128 + col) * 128 + kk * 32 + kg * 8;
#pragma unroll
      for (int e = 0; e < 8; ++e) wf[gi][kk][e] = (short)f2bf(p[e]);
    }
  for (int i = tid; i < 4096; i += 512) ((unsigned short*)hb)[i] = 0;
  float c[4] = {0.f, 0.f, 0.f, 0.f};

  const float* pbase = pre + ((size_t)(wg * 16 + rbase)) * 512 + col;
  float pf[16];
#pragma unroll
  for (int gi = 0; gi < 4; ++gi)
#pragma unroll
    for (int e = 0; e < 4; ++e) pf[gi * 4 + e] = pbase[e * 512 + gi * 128];
  __syncthreads();

  for (int t = 0; t < T; ++t) {
    const unsigned short* hc = hb[t & 1];
    unsigned short* hn = hb[(t & 1) ^ 1];
    s16x8 a[4];
#pragma unroll
    for (int kk = 0; kk < 4; ++kk) {
      const int byt = lr * 256 + ((kk * 64 + kg * 16) ^ ((lr & 7) << 4));
      a[kk] = *(const s16x8*)((const char*)hc + byt);
    }
    f32x4 acc[4];
#pragma unroll
    for (int gi = 0; gi < 4; ++gi)
      acc[gi] = (f32x4){pf[gi * 4], pf[gi * 4 + 1], pf[gi * 4 + 2], pf[gi * 4 + 3]};
    float pfn[16];
    if (t + 1 < T) {
      const float* pb2 = pbase + (size_t)(t + 1) * 65536;
#pragma unroll
      for (int gi = 0; gi < 4; ++gi)
#pragma unroll
        for (int e = 0; e < 4; ++e) pfn[gi * 4 + e] = pb2[e * 512 + gi * 128];
    } else {
#pragma unroll
      for (int i2 = 0; i2 < 16; ++i2) pfn[i2] = 0.f;
    }
#pragma unroll
    for (int kk = 0; kk < 4; ++kk)
#pragma unroll
      for (int gi = 0; gi < 4; ++gi)
        acc[gi] = __builtin_amdgcn_mfma_f32_16x16x32_bf16(a[kk], wf[gi][kk], acc[gi], 0, 0, 0);
#pragma unroll
    for (int e = 0; e < 4; ++e) {
      float gi_ = sigf(acc[0][e]);
      float gf  = sigf(acc[1][e]);
      float gg  = tanhf_(acc[2][e]);
      float go  = sigf(acc[3][e]);
      c[e] = gf * c[e] + gi_ * gg;
      float h = go * tanhf_(c[e]);
      unsigned short hu = f2bf(h);
      int row = rbase + e;
      int byt = row * 256 + ((col * 2) ^ ((row & 7) << 4));
      *(unsigned short*)((char*)hn + byt) = hu;
      hs[((size_t)t * 128 + wg * 16 + row) * 128 + col] = hu;
    }
#pragma unroll
    for (int i2 = 0; i2 < 16; ++i2) pf[i2] = pfn[i2];
    __syncthreads();
  }
}

// ---------------------------------------------------------------- persistent decoder
// 256 WGs (1/CU, LDS-bound). Every WG: attn for (b=g>>1, half=g&1) with K/V in LDS.
// WGs 0-7 are ALSO "drivers": each owns 16 batches and runs BOTH LSTM layers,
// q-proj, Wo and lin entirely locally (weights in VGPRs, h0/h1 in LDS).
// Chain per step: driver(LSTM0,LSTM1,q) -> fQ -> attn(256 WGs) -> fC -> driver(Wo,lin).
// Flags: single-writer release stores; pollers use RELAXED loads + one acquire fence.

__device__ __forceinline__ void attn_step(
    int s, int b, int half, int tid, int l, int wv,
    const unsigned* fQb, unsigned* fCg,
    const float* qg, float* ctvg,
    const unsigned short* Kl, const unsigned short* Vl,
    float* sc, float* qx, float* red, float* mxs, float* isl)
{
  if (tid == 0) wait_flag(fQb, (unsigned)s);
  __syncthreads();
  if (tid < 64) qx[tid] = aloadf(&qg[(size_t)b * 128 + half * 64 + tid]);
  __syncthreads();
  const int t = tid;
  float s2[2] = {0.f, 0.f};
#pragma unroll
  for (int c = 0; c < 8; ++c) {
    const s16x8 kv = *(const s16x8*)((const char*)Kl + t * 128 + (((c + t) & 7) << 4));
    float d = 0.f;
#pragma unroll
    for (int e = 0; e < 8; ++e) d += qx[c * 8 + e] * bf2f(kv[e]);
    s2[c >> 2] += d;
  }
  const float scale = 0.1767766952966369f;  // 1/sqrt(32)
  s2[0] *= scale; s2[1] *= scale;
#pragma unroll
  for (int hh = 0; hh < 2; ++hh) {
    float m = s2[hh];
#pragma unroll
    for (int off = 32; off > 0; off >>= 1) m = fmaxf(m, __shfl_xor(m, off));
    if (l == 0) red[hh * 8 + wv] = m;
  }
  __syncthreads();
  if (tid < 2) {
    float m = red[tid * 8];
#pragma unroll
    for (int w2 = 1; w2 < 8; ++w2) m = fmaxf(m, red[tid * 8 + w2]);
    mxs[tid] = m;
  }
  __syncthreads();
#pragma unroll
  for (int hh = 0; hh < 2; ++hh) {
    float p = __expf(s2[hh] - mxs[hh]);
    sc[hh * 512 + t] = p;
    float ps = p;
#pragma unroll
    for (int off = 32; off > 0; off >>= 1) ps += __shfl_xor(ps, off);
    if (l == 0) red[16 + hh * 8 + wv] = ps;
  }
  __syncthreads();
  if (tid < 2) {
    float sm = red[16 + tid * 8];
#pragma unroll
    for (int w2 = 1; w2 < 8; ++w2) sm += red[16 + tid * 8 + w2];
    isl[tid] = 1.f / sm;
  }
  __syncthreads();
  {
    const int hh = tid >> 8, dg = (tid >> 6) & 3, tc = tid & 63;
    const int c = hh * 4 + dg;
    float a8[8] = {0.f, 0.f, 0.f, 0.f, 0.f, 0.f, 0.f, 0.f};
#pragma unroll
    for (int tt = 0; tt < 8; ++tt) {
      const int tr = tc * 8 + ((tt + tc) & 7);
      const s16x8 vv = *(const s16x8*)((const char*)Vl + tr * 128 + (((c + tr) & 7) << 4));
      const float p = sc[hh * 512 + tr];
#pragma unroll
      for (int e = 0; e < 8; ++e) a8[e] += p * bf2f(vv[e]);
    }
#pragma unroll
    for (int off = 32; off > 0; off >>= 1)
#pragma unroll
      for (int e = 0; e < 8; ++e) a8[e] += __shfl_xor(a8[e], off);
    if (tc == 0) {
      const float iv = isl[hh];
#pragma unroll
      for (int e = 0; e < 8; ++e)
        astoref(&ctvg[(size_t)b * 128 + half * 64 + c * 8 + e], a8[e] * iv);
    }
  }
  __syncthreads();
  if (tid == 0) flag_set(fCg, (unsigned)(s + 1));
}

#define DEC_SMEM 157440

__global__ void __launch_bounds__(512, 1) decoder_persist(
    const unsigned short* __restrict__ kb, const unsigned short* __restrict__ vb,
    const unsigned short* __restrict__ W0p, const unsigned short* __restrict__ Wh0,
    const unsigned short* __restrict__ Wi1, const unsigned short* __restrict__ Wh1,
    const unsigned short* __restrict__ Wqd, const unsigned short* __restrict__ Wod,
    const float* __restrict__ b0, const float* __restrict__ b1,
    const float* __restrict__ bq, const float* __restrict__ bo,
    const float* __restrict__ linW, const float* __restrict__ linb,
    float* __restrict__ qg, float* __restrict__ ctvg,
    unsigned* __restrict__ flags, float* __restrict__ out)
{
  extern __shared__ char smem[];
  unsigned short* Kl = (unsigned short*)smem;              // [512][64] skewed
  unsigned short* Vl = (unsigned short*)(smem + 65536);    // [512][64] skewed
  float* sc   = (float*)(smem + 131072);                   // [2][512]
  float* qx   = (float*)(smem + 135168);                   // [64]
  float* red  = (float*)(smem + 135424);                   // [32]
  float* mxs  = (float*)(smem + 135552);                   // [2]
  float* isl  = (float*)(smem + 135560);                   // [2]
  unsigned short* xint = (unsigned short*)(smem + 135680); // [16][160] bf16
  unsigned short* ht0  = (unsigned short*)(smem + 140800); // [16][128] bf16
  unsigned short* ht1  = (unsigned short*)(smem + 144896); // [16][128] bf16
  float* P = (float*)(smem + 148992);                      // [16][132] f32 (ctv, then ct)

  const int g = blockIdx.x;
  const int tid = threadIdx.x;
  const int b = g >> 1, half = g & 1;
  const int l = tid & 63, wv = tid >> 6;
  const int lr = l & 15, kg = l >> 4;
  const int col = wv * 16 + lr;
  const int rbase = kg * 4;
  unsigned* fQ = flags;            // 128 flags, stride 16 u32
  unsigned* fC = flags + 2048;     // 256 flags, stride 16 u32
  const unsigned* fQb = fQ + (size_t)b * 16;
  unsigned* fCg = fC + (size_t)g * 16;

  // one-time K/V load into LDS (row t: 8 16B octets, skew slot=(c+t)&7)
  {
    const int t = tid;
    const unsigned short* krow = kb + ((size_t)t * 128 + b) * 128 + half * 64;
    const unsigned short* vrow = vb + ((size_t)t * 128 + b) * 128 + half * 64;
#pragma unroll
    for (int c = 0; c < 8; ++c) {
      const s16x8 kv = *(const s16x8*)(krow + c * 8);
      const s16x8 vv = *(const s16x8*)(vrow + c * 8);
      const int sl = ((c + t) & 7) << 4;
      *(s16x8*)((char*)Kl + t * 128 + sl) = kv;
      *(s16x8*)((char*)Vl + t * 128 + sl) = vv;
    }
  }

  if (g < 8) {
    // ---- driver WG: both LSTM layers + q + Wo + lin for b in [g*16, g*16+16)
    const int b016 = g * 16;
    s16x8 wf0[4][5], wfh[4][4], wi1f[4][4], wh1f[4][4], wqf[4], wof[4];
    float b0v[4], b1v[4], c0r[4], c1r[4];
#pragma unroll
    for (int gi = 0; gi < 4; ++gi) {
#pragma unroll
      for (int kk = 0; kk < 5; ++kk)
        wf0[gi][kk] = *(const s16x8*)(W0p + (size_t)(gi * 128 + col) * 160 + kk * 32 + kg * 8);
#pragma unroll
      for (int kk = 0; kk < 4; ++kk) {
        wfh[gi][kk]  = *(const s16x8*)(Wh0 + (size_t)(gi * 128 + col) * 128 + kk * 32 + kg * 8);
        wi1f[gi][kk] = *(const s16x8*)(Wi1 + (size_t)(gi * 128 + col) * 128 + kk * 32 + kg * 8);
        wh1f[gi][kk] = *(const s16x8*)(Wh1 + (size_t)(gi * 128 + col) * 128 + kk * 32 + kg * 8);
      }
      b0v[gi] = b0[gi * 128 + col];
      b1v[gi] = b1[gi * 128 + col];
      c0r[gi] = 0.f; c1r[gi] = 0.f;
    }
#pragma unroll
    for (int kk = 0; kk < 4; ++kk) {
      wqf[kk] = *(const s16x8*)(Wqd + (size_t)col * 128 + kk * 32 + kg * 8);
      wof[kk] = *(const s16x8*)(Wod + (size_t)col * 128 + kk * 32 + kg * 8);
    }
    const float bqv_ = bq[col];
    const float bov_ = bo[col];
    for (int i = tid; i < 2560; i += 512) xint[i] = 0;
    for (int i = tid; i < 2048; i += 512) { ht0[i] = 0; ht1[i] = 0; }
    __syncthreads();

    for (int s = 0; s < 64; ++s) {
      // ---- layer 0: gates = W0.xin + Wh0.h0
      s16x8 ax[5], ah[4];
#pragma unroll
      for (int kk = 0; kk < 5; ++kk)
        ax[kk] = *(const s16x8*)((const char*)xint + lr * 320 + kk * 64 + kg * 16);
#pragma unroll
      for (int kk = 0; kk < 4; ++kk)
        ah[kk] = *(const s16x8*)((const char*)ht0 + lr * 256 + kk * 64 + kg * 16);
      f32x4 acc[4];
#pragma unroll
      for (int gi = 0; gi < 4; ++gi) acc[gi] = (f32x4){b0v[gi], b0v[gi], b0v[gi], b0v[gi]};
#pragma unroll
      for (int kk = 0; kk < 5; ++kk)
#pragma unroll
        for (int gi = 0; gi < 4; ++gi)
          acc[gi] = __builtin_amdgcn_mfma_f32_16x16x32_bf16(ax[kk], wf0[gi][kk], acc[gi], 0, 0, 0);
#pragma unroll
      for (int kk = 0; kk < 4; ++kk)
#pragma unroll
        for (int gi = 0; gi < 4; ++gi)
          acc[gi] = __builtin_amdgcn_mfma_f32_16x16x32_bf16(ah[kk], wfh[gi][kk], acc[gi], 0, 0, 0);
      __syncthreads();   // ht0 reads done
#pragma unroll
      for (int e = 0; e < 4; ++e) {
        const float gi_ = sigf(acc[0][e]), gf = sigf(acc[1][e]);
        const float gg = tanhf_(acc[2][e]), go = sigf(acc[3][e]);
        c0r[e] = gf * c0r[e] + gi_ * gg;
        ht0[(rbase + e) * 128 + col] = f2bf(go * tanhf_(c0r[e]));
      }
      __syncthreads();

      // ---- layer 1: gates = Wi1.h0 + Wh1.h1
      s16x8 ah0[4], ah1[4];
#pragma unroll
      for (int kk = 0; kk < 4; ++kk) {
        ah0[kk] = *(const s16x8*)((const char*)ht0 + lr * 256 + kk * 64 + kg * 16);
        ah1[kk] = *(const s16x8*)((const char*)ht1 + lr * 256 + kk * 64 + kg * 16);
      }
#pragma unroll
      for (int gi = 0; gi < 4; ++gi) acc[gi] = (f32x4){b1v[gi], b1v[gi], b1v[gi], b1v[gi]};
#pragma unroll
      for (int kk = 0; kk < 4; ++kk)
#pragma unroll
        for (int gi = 0; gi < 4; ++gi) {
          acc[gi] = __builtin_amdgcn_mfma_f32_16x16x32_bf16(ah0[kk], wi1f[gi][kk], acc[gi], 0, 0, 0);
          acc[gi] = __builtin_amdgcn_mfma_f32_16x16x32_bf16(ah1[kk], wh1f[gi][kk], acc[gi], 0, 0, 0);
        }
      __syncthreads();   // ht1 reads done
#pragma unroll
      for (int e = 0; e < 4; ++e) {
        const float gi_ = sigf(acc[0][e]), gf = sigf(acc[1][e]);
        const float gg = tanhf_(acc[2][e]), go = sigf(acc[3][e]);
        c1r[e] = gf * c1r[e] + gi_ * gg;
        ht1[(rbase + e) * 128 + col] = f2bf(go * tanhf_(c1r[e]));
      }
      __syncthreads();

      // ---- q = Wq.h1 + bq -> qg (f32, relaxed agent stores)
      s16x8 aq[4];
#pragma unroll
      for (int kk = 0; kk < 4; ++kk)
        aq[kk] = *(const s16x8*)((const char*)ht1 + lr * 256 + kk * 64 + kg * 16);
      f32x4 qa = (f32x4){bqv_, bqv_, bqv_, bqv_};
#pragma unroll
      for (int kk = 0; kk < 4; ++kk)
        qa = __builtin_amdgcn_mfma_f32_16x16x32_bf16(aq[kk], wqf[kk], qa, 0, 0, 0);
#pragma unroll
      for (int e = 0; e < 4; ++e)
        astoref(&qg[(size_t)(b016 + rbase + e) * 128 + col], qa[e]);
      __syncthreads();   // all q stores drained (vmcnt at barrier)
      if (tid < 16) flag_set(fQ + (size_t)(b016 + tid) * 16, (unsigned)(s + 1));

      // ---- own attention slice (overlaps other WGs' attention)
      attn_step(s, b, half, tid, l, wv, fQb, fCg, qg, ctvg, Kl, Vl, sc, qx, red, mxs, isl);

      // ---- wait for all 32 ctv producers of this batch group
      if (tid < 32) {
        const unsigned* fp = fC + (size_t)(g * 32 + tid) * 16;
        while (__hip_atomic_load(fp, __ATOMIC_RELAXED, __HIP_MEMORY_SCOPE_AGENT) <= (unsigned)s) {}
        __builtin_amdgcn_fence(__ATOMIC_ACQUIRE, "agent");
      }
      __syncthreads();
      // gather ctv rows into P (row stride 132 f32 = 66 u64, kills bank conflicts)
      for (int i = tid; i < 1024; i += 512) {
        const int r = i >> 6, c2 = i & 63;
        ((unsigned long long*)P)[r * 66 + c2] =
            aload64((const unsigned long long*)ctvg + (size_t)b016 * 64 + i);
      }
      __syncthreads();
      // ---- ct = Wo.ctv + bo
      s16x8 act[4];
#pragma unroll
      for (int kk = 0; kk < 4; ++kk) {
        s16x8 r;
#pragma unroll
        for (int e = 0; e < 8; ++e) r[e] = (short)f2bf(P[lr * 132 + kk * 32 + kg * 8 + e]);
        act[kk] = r;
      }
      f32x4 acd = (f32x4){bov_, bov_, bov_, bov_};
#pragma unroll
      for (int kk = 0; kk < 4; ++kk)
        acd = __builtin_amdgcn_mfma_f32_16x16x32_bf16(act[kk], wof[kk], acd, 0, 0, 0);
      __syncthreads();   // P (ctv) reads done
#pragma unroll
      for (int e = 0; e < 4; ++e) {
        P[(rbase + e) * 132 + col] = acd[e];
        xint[(rbase + e) * 160 + 4 + col] = f2bf(acd[e]);
      }
      __syncthreads();
      // ---- y = [h1, ct] @ lin_W.T + lin_b : thread (bl, o, kc)
      {
        const int bl = tid >> 5, o = (tid >> 3) & 3, kc = tid & 7;
        const float* lw = linW + o * 256;
        float part = 0.f;
#pragma unroll
        for (int k2 = 0; k2 < 16; ++k2) {
          const int k = kc * 16 + k2;
          part += bf2f((short)ht1[bl * 128 + k]) * lw[k] + P[bl * 132 + k] * lw[128 + k];
        }
        part += __shfl_xor(part, 1);
        part += __shfl_xor(part, 2);
        part += __shfl_xor(part, 4);
        if (kc == 0) {
          const float yv = part + linb[o];
          out[((size_t)s * 128 + b016 + bl) * 4 + o] = yv;
          xint[bl * 160 + o] = f2bf(yv);
        }
      }
      __syncthreads();
    }
  } else {
    for (int s = 0; s < 64; ++s)
      attn_step(s, b, half, tid, l, wv, fQb, fCg, qg, ctvg, Kl, Vl, sc, qx, red, mxs, isl);
  }
}

// ---------------------------------------------------------------- launch
extern "C" void kernel_launch(void* const* d_in, const int* in_sizes, int n_in,
                              void* d_out, int out_size, void* d_ws, size_t ws_size,
                              hipStream_t stream) {
  (void)in_sizes; (void)n_in; (void)out_size; (void)ws_size;
  const float* x     = (const float*)d_in[0];
  const float* eWih0 = (const float*)d_in[1];
  const float* eWhh0 = (const float*)d_in[2];
  const float* eb0   = (const float*)d_in[3];
  const float* eWih1 = (const float*)d_in[4];
  const float* eWhh1 = (const float*)d_in[5];
  const float* eb1   = (const float*)d_in[6];
  const float* dWih0 = (const float*)d_in[7];
  const float* dWhh0 = (const float*)d_in[8];
  const float* db0   = (const float*)d_in[9];
  const float* dWih1 = (const float*)d_in[10];
  const float* dWhh1 = (const float*)d_in[11];
  const float* db1   = (const float*)d_in[12];
  const float* Wq    = (const float*)d_in[13];
  const float* bq    = (const float*)d_in[14];
  const float* Wk    = (const float*)d_in[15];
  const float* bk    = (const float*)d_in[16];
  const float* Wv    = (const float*)d_in[17];
  const float* bv    = (const float*)d_in[18];
  const float* Wo    = (const float*)d_in[19];
  const float* bo    = (const float*)d_in[20];
  const float* linW  = (const float*)d_in[21];
  const float* linb  = (const float*)d_in[22];

  char* w = (char*)d_ws;
  unsigned* flags = (unsigned*)w;                        // 32 KB flag region (64B-strided)
  float* qg   = (float*)(w + 65536);                     // 64 KB
  float* ctvg = (float*)(w + 131072);                    // 64 KB
  float* pre  = (float*)(w + 524288);                    // 128 MB
  size_t off = 524288 + (size_t)65536 * 512 * 4;
  unsigned short* hs0  = (unsigned short*)(w + off); off += (size_t)65536 * 128 * 2;
  unsigned short* enc  = (unsigned short*)(w + off); off += (size_t)65536 * 128 * 2;
  unsigned short* kbuf = (unsigned short*)(w + off); off += (size_t)65536 * 128 * 2;
  unsigned short* vbuf = (unsigned short*)(w + off); off += (size_t)65536 * 128 * 2;
  unsigned short* W0p  = (unsigned short*)(w + off); off += 512 * 160 * 2;
  unsigned short* Wh0d = (unsigned short*)(w + off); off += 512 * 128 * 2;
  unsigned short* Wi1d = (unsigned short*)(w + off); off += 512 * 128 * 2;
  unsigned short* Wh1d = (unsigned short*)(w + off); off += 512 * 128 * 2;
  unsigned short* Wqd  = (unsigned short*)(w + off); off += 128 * 128 * 2;
  unsigned short* Wod  = (unsigned short*)(w + off); off += 128 * 128 * 2;

  hipMemsetAsync(w, 0, 32768, stream);  // zero flags every call

  conv_pad<<<(512 * 160 + 255) / 256, 256, 0, stream>>>(dWih0, W0p, 512, 132, 160);
  conv_pad<<<(512 * 128 + 255) / 256, 256, 0, stream>>>(dWhh0, Wh0d, 512, 128, 128);
  conv_pad<<<(512 * 128 + 255) / 256, 256, 0, stream>>>(dWih1, Wi1d, 512, 128, 128);
  conv_pad<<<(512 * 128 + 255) / 256, 256, 0, stream>>>(dWhh1, Wh1d, 512, 128, 128);
  conv_pad<<<(128 * 128 + 255) / 256, 256, 0, stream>>>(Wq, Wqd, 128, 128, 128);
  conv_pad<<<(128 * 128 + 255) / 256, 256, 0, stream>>>(Wo, Wod, 128, 128, 128);

  // encoder
  gemm_bt<0, 0><<<dim3(4, 512), 256, 0, stream>>>((const void*)x, eWih0, eb0, (void*)pre, 65536, 512, 1024);
  lstm_scan<<<8, 512, 0, stream>>>(pre, eWhh0, hs0, 512);
  gemm_bt<1, 0><<<dim3(4, 512), 256, 0, stream>>>((const void*)hs0, eWih1, eb1, (void*)pre, 65536, 512, 128);
  lstm_scan<<<8, 512, 0, stream>>>(pre, eWhh1, enc, 512);
  // K/V projections
  gemm_bt<1, 1><<<dim3(1, 512), 256, 0, stream>>>((const void*)enc, Wk, bk, (void*)kbuf, 65536, 128, 128);
  gemm_bt<1, 1><<<dim3(1, 512), 256, 0, stream>>>((const void*)enc, Wv, bv, (void*)vbuf, 65536, 128, 128);

  // persistent decoder: 256 WGs = 1/CU, big dynamic LDS
  hipFuncSetAttribute((const void*)decoder_persist,
                      hipFuncAttributeMaxDynamicSharedMemorySize, DEC_SMEM);
  decoder_persist<<<256, 512, DEC_SMEM, stream>>>(kbuf, vbuf, W0p, Wh0d, Wi1d, Wh1d, Wqd, Wod,
      db0, db1, bq, bo, linW, linb, qg, ctvg, flags, (float*)d_out);
}

// Round 7
// 3984.125 us; speedup vs baseline: 3.2584x; 1.0443x over previous
//
#include <hip/hip_runtime.h>
#include <hip/hip_bf16.h>

typedef __attribute__((ext_vector_type(8))) short s16x8;
typedef __attribute__((ext_vector_type(4))) float f32x4;

__device__ inline unsigned short f2bf(float f) {
  unsigned u = __builtin_bit_cast(unsigned, f);
  unsigned r = (u + 0x7FFFu + ((u >> 16) & 1u)) >> 16;  // RTNE
  return (unsigned short)r;
}
__device__ inline float bf2f(short v) {
  return __builtin_bit_cast(float, ((unsigned)(unsigned short)v) << 16);
}
__device__ inline float sigf(float x) { return 1.f / (1.f + __expf(-x)); }
__device__ inline float tanhf_(float x) { float e = __expf(2.f * x); return 1.f - 2.f / (e + 1.f); }

// All cross-WG data moves through agent-scope atomics (sc1 -> performed at the
// LLC coherence point, never stale L2). Therefore NO release/acquire cache
// maintenance (buffer_wbl2 / buffer_inv) is needed anywhere:
//   producer: s_waitcnt vmcnt(0)  (own sc1 stores complete)  -> relaxed flag store
//   consumer: relaxed poll -> __syncthreads() -> relaxed data loads
__device__ inline unsigned long long aload64(const unsigned long long* p) {
  return __hip_atomic_load(p, __ATOMIC_RELAXED, __HIP_MEMORY_SCOPE_AGENT);
}
__device__ inline float aloadf(const float* p) {
  return __hip_atomic_load(p, __ATOMIC_RELAXED, __HIP_MEMORY_SCOPE_AGENT);
}
__device__ inline void astoref(float* p, float v) {
  __hip_atomic_store(p, v, __ATOMIC_RELAXED, __HIP_MEMORY_SCOPE_AGENT);
}
__device__ inline void flag_set_fast(unsigned* p, unsigned v) {
  asm volatile("s_waitcnt vmcnt(0)" ::: "memory");
  __hip_atomic_store(p, v, __ATOMIC_RELAXED, __HIP_MEMORY_SCOPE_AGENT);
}
__device__ inline void wait_flag(const unsigned* p, unsigned s) {
  while (__hip_atomic_load(p, __ATOMIC_RELAXED, __HIP_MEMORY_SCOPE_AGENT) <= s) {}
}

// ---------------------------------------------------------------- conv/pad
__global__ void conv_pad(const float* __restrict__ src, unsigned short* __restrict__ dst,
                         int rows, int scols, int dcols) {
  int i = blockIdx.x * 256 + threadIdx.x;
  if (i >= rows * dcols) return;
  int r = i / dcols, cc = i % dcols;
  dst[i] = (cc < scols) ? f2bf(src[(size_t)r * scols + cc]) : (unsigned short)0;
}

// ---------------------------------------------------------------- GEMM C = A @ B^T + bias
#define BM 128
#define BN 128
#define BKK 32

template<int A_BF16, int C_BF16>
__global__ __launch_bounds__(256) void gemm_bt(const void* __restrict__ Av,
    const float* __restrict__ B, const float* __restrict__ bias,
    void* __restrict__ Cv, int M, int N, int K) {
  __shared__ short sA[BM * BKK];
  __shared__ short sB[BN * BKK];
  const int tid = threadIdx.x;
  const int l = tid & 63;
  const int wid = tid >> 6;
  const int wr = wid >> 1, wc = wid & 1;
  const int lr = l & 15, kg = l >> 4;
  const int bn = blockIdx.x, bm = blockIdx.y;
  const int arow = tid >> 1;
  const int acol = (tid & 1) * 16;

  f32x4 acc[4][4];
#pragma unroll
  for (int i = 0; i < 4; ++i)
#pragma unroll
    for (int j = 0; j < 4; ++j) acc[i][j] = (f32x4){0.f, 0.f, 0.f, 0.f};

  for (int kt = 0; kt < K; kt += BKK) {
    __syncthreads();
    if (A_BF16) {
      const unsigned short* src = (const unsigned short*)Av + (size_t)(bm * BM + arow) * K + kt + acol;
      *(s16x8*)&sA[arow * BKK + acol] = *(const s16x8*)src;
      *(s16x8*)&sA[arow * BKK + acol + 8] = *(const s16x8*)(src + 8);
    } else {
      const float* src = (const float*)Av + (size_t)(bm * BM + arow) * K + kt + acol;
      s16x8 v0, v1;
#pragma unroll
      for (int e = 0; e < 8; ++e) { v0[e] = (short)f2bf(src[e]); v1[e] = (short)f2bf(src[8 + e]); }
      *(s16x8*)&sA[arow * BKK + acol] = v0;
      *(s16x8*)&sA[arow * BKK + acol + 8] = v1;
    }
    {
      const float* src = B + (size_t)(bn * BN + arow) * K + kt + acol;
      s16x8 v0, v1;
#pragma unroll
      for (int e = 0; e < 8; ++e) { v0[e] = (short)f2bf(src[e]); v1[e] = (short)f2bf(src[8 + e]); }
      *(s16x8*)&sB[arow * BKK + acol] = v0;
      *(s16x8*)&sB[arow * BKK + acol + 8] = v1;
    }
    __syncthreads();
    s16x8 af[4], bfr[4];
#pragma unroll
    for (int mi = 0; mi < 4; ++mi)
      af[mi] = *(const s16x8*)&sA[(wr * 64 + mi * 16 + lr) * BKK + kg * 8];
#pragma unroll
    for (int ni = 0; ni < 4; ++ni)
      bfr[ni] = *(const s16x8*)&sB[(wc * 64 + ni * 16 + lr) * BKK + kg * 8];
#pragma unroll
    for (int mi = 0; mi < 4; ++mi)
#pragma unroll
      for (int ni = 0; ni < 4; ++ni)
        acc[mi][ni] = __builtin_amdgcn_mfma_f32_16x16x32_bf16(af[mi], bfr[ni], acc[mi][ni], 0, 0, 0);
  }
  const int r0 = bm * BM + wr * 64;
  const int c0 = bn * BN + wc * 64;
#pragma unroll
  for (int mi = 0; mi < 4; ++mi)
#pragma unroll
    for (int ni = 0; ni < 4; ++ni) {
      const int col = c0 + ni * 16 + lr;
      const float bv = bias[col];
#pragma unroll
      for (int e = 0; e < 4; ++e) {
        const int row = r0 + mi * 16 + kg * 4 + e;
        const float v = acc[mi][ni][e] + bv;
        if (C_BF16) ((unsigned short*)Cv)[(size_t)row * N + col] = f2bf(v);
        else        ((float*)Cv)[(size_t)row * N + col] = v;
      }
    }
}

// ---------------------------------------------------------------- encoder LSTM scan
__global__ __launch_bounds__(512) void lstm_scan(const float* __restrict__ pre,
    const float* __restrict__ Whh, unsigned short* __restrict__ hs, int T) {
  __shared__ unsigned short hb[2][2048];
  const int tid = threadIdx.x;
  const int l = tid & 63, w = tid >> 6;
  const int wg = blockIdx.x;
  const int lr = l & 15, kg = l >> 4;
  const int col = w * 16 + lr;
  const int rbase = kg * 4;

  s16x8 wf[4][4];
#pragma unroll
  for (int gi = 0; gi < 4; ++gi)
#pragma unroll
    for (int kk = 0; kk < 4; ++kk) {
      const float* p = Whh + (size_t)(gi * 128 + col) * 128 + kk * 32 + kg * 8;
#pragma unroll
      for (int e = 0; e < 8; ++e) wf[gi][kk][e] = (short)f2bf(p[e]);
    }
  for (int i = tid; i < 4096; i += 512) ((unsigned short*)hb)[i] = 0;
  float c[4] = {0.f, 0.f, 0.f, 0.f};

  const float* pbase = pre + ((size_t)(wg * 16 + rbase)) * 512 + col;
  float pf[16];
#pragma unroll
  for (int gi = 0; gi < 4; ++gi)
#pragma unroll
    for (int e = 0; e < 4; ++e) pf[gi * 4 + e] = pbase[e * 512 + gi * 128];
  __syncthreads();

  for (int t = 0; t < T; ++t) {
    const unsigned short* hc = hb[t & 1];
    unsigned short* hn = hb[(t & 1) ^ 1];
    s16x8 a[4];
#pragma unroll
    for (int kk = 0; kk < 4; ++kk) {
      const int byt = lr * 256 + ((kk * 64 + kg * 16) ^ ((lr & 7) << 4));
      a[kk] = *(const s16x8*)((const char*)hc + byt);
    }
    f32x4 acc[4];
#pragma unroll
    for (int gi = 0; gi < 4; ++gi)
      acc[gi] = (f32x4){pf[gi * 4], pf[gi * 4 + 1], pf[gi * 4 + 2], pf[gi * 4 + 3]};
    float pfn[16];
    if (t + 1 < T) {
      const float* pb2 = pbase + (size_t)(t + 1) * 65536;
#pragma unroll
      for (int gi = 0; gi < 4; ++gi)
#pragma unroll
        for (int e = 0; e < 4; ++e) pfn[gi * 4 + e] = pb2[e * 512 + gi * 128];
    } else {
#pragma unroll
      for (int i2 = 0; i2 < 16; ++i2) pfn[i2] = 0.f;
    }
#pragma unroll
    for (int kk = 0; kk < 4; ++kk)
#pragma unroll
      for (int gi = 0; gi < 4; ++gi)
        acc[gi] = __builtin_amdgcn_mfma_f32_16x16x32_bf16(a[kk], wf[gi][kk], acc[gi], 0, 0, 0);
#pragma unroll
    for (int e = 0; e < 4; ++e) {
      float gi_ = sigf(acc[0][e]);
      float gf  = sigf(acc[1][e]);
      float gg  = tanhf_(acc[2][e]);
      float go  = sigf(acc[3][e]);
      c[e] = gf * c[e] + gi_ * gg;
      float h = go * tanhf_(c[e]);
      unsigned short hu = f2bf(h);
      int row = rbase + e;
      int byt = row * 256 + ((col * 2) ^ ((row & 7) << 4));
      *(unsigned short*)((char*)hn + byt) = hu;
      hs[((size_t)t * 128 + wg * 16 + row) * 128 + col] = hu;
    }
#pragma unroll
    for (int i2 = 0; i2 < 16; ++i2) pf[i2] = pfn[i2];
    __syncthreads();
  }
}

// ---------------------------------------------------------------- persistent decoder
// 256 WGs (1/CU, LDS-bound). Every WG: attn for (b=g>>1, half=g&1) with K/V in LDS.
// WGs 0-7 are "drivers": both LSTM layers + q + Wo + lin for 16 batches each.
// Chain per step: driver(LSTM0,LSTM1,q) -> fQ -> attn(256 WGs) -> fC -> driver(Wo,lin).
// Fence-free sc1 protocol (see helpers above).

__device__ __forceinline__ void attn_step(
    int s, int b, int half, int tid, int l, int wv,
    const unsigned* fQb, unsigned* fCg,
    const float* qg, float* ctvg,
    const unsigned short* Kl, const unsigned short* Vl,
    float* sc, float* qx, float* red, float* mxs, float* isl)
{
  if (tid == 0) wait_flag(fQb, (unsigned)s);
  __syncthreads();
  if (tid < 64) qx[tid] = aloadf(&qg[(size_t)b * 128 + half * 64 + tid]);
  __syncthreads();
  const int t = tid;
  float s2[2] = {0.f, 0.f};
#pragma unroll
  for (int c = 0; c < 8; ++c) {
    const s16x8 kv = *(const s16x8*)((const char*)Kl + t * 128 + (((c + t) & 7) << 4));
    float d = 0.f;
#pragma unroll
    for (int e = 0; e < 8; ++e) d += qx[c * 8 + e] * bf2f(kv[e]);
    s2[c >> 2] += d;
  }
  const float scale = 0.1767766952966369f;  // 1/sqrt(32)
  s2[0] *= scale; s2[1] *= scale;
#pragma unroll
  for (int hh = 0; hh < 2; ++hh) {
    float m = s2[hh];
#pragma unroll
    for (int off = 32; off > 0; off >>= 1) m = fmaxf(m, __shfl_xor(m, off));
    if (l == 0) red[hh * 8 + wv] = m;
  }
  __syncthreads();
  if (tid < 2) {
    float m = red[tid * 8];
#pragma unroll
    for (int w2 = 1; w2 < 8; ++w2) m = fmaxf(m, red[tid * 8 + w2]);
    mxs[tid] = m;
  }
  __syncthreads();
#pragma unroll
  for (int hh = 0; hh < 2; ++hh) {
    float p = __expf(s2[hh] - mxs[hh]);
    sc[hh * 512 + t] = p;
    float ps = p;
#pragma unroll
    for (int off = 32; off > 0; off >>= 1) ps += __shfl_xor(ps, off);
    if (l == 0) red[16 + hh * 8 + wv] = ps;
  }
  __syncthreads();
  if (tid < 2) {
    float sm = red[16 + tid * 8];
#pragma unroll
    for (int w2 = 1; w2 < 8; ++w2) sm += red[16 + tid * 8 + w2];
    isl[tid] = 1.f / sm;
  }
  __syncthreads();
  {
    const int hh = tid >> 8, dg = (tid >> 6) & 3, tc = tid & 63;
    const int c = hh * 4 + dg;
    float a8[8] = {0.f, 0.f, 0.f, 0.f, 0.f, 0.f, 0.f, 0.f};
#pragma unroll
    for (int tt = 0; tt < 8; ++tt) {
      const int tr = tc * 8 + ((tt + tc) & 7);
      const s16x8 vv = *(const s16x8*)((const char*)Vl + tr * 128 + (((c + tr) & 7) << 4));
      const float p = sc[hh * 512 + tr];
#pragma unroll
      for (int e = 0; e < 8; ++e) a8[e] += p * bf2f(vv[e]);
    }
#pragma unroll
    for (int off = 32; off > 0; off >>= 1)
#pragma unroll
      for (int e = 0; e < 8; ++e) a8[e] += __shfl_xor(a8[e], off);
    if (tc == 0) {
      const float iv = isl[hh];
#pragma unroll
      for (int e = 0; e < 8; ++e)
        astoref(&ctvg[(size_t)b * 128 + half * 64 + c * 8 + e], a8[e] * iv);
    }
  }
  __syncthreads();
  if (tid == 0) flag_set_fast(fCg, (unsigned)(s + 1));
}

#define DEC_SMEM 157440

__global__ void __launch_bounds__(512, 1) decoder_persist(
    const unsigned short* __restrict__ kb, const unsigned short* __restrict__ vb,
    const unsigned short* __restrict__ W0p, const unsigned short* __restrict__ Wh0,
    const unsigned short* __restrict__ Wi1, const unsigned short* __restrict__ Wh1,
    const unsigned short* __restrict__ Wqd, const unsigned short* __restrict__ Wod,
    const float* __restrict__ b0, const float* __restrict__ b1,
    const float* __restrict__ bq, const float* __restrict__ bo,
    const float* __restrict__ linW, const float* __restrict__ linb,
    float* __restrict__ qg, float* __restrict__ ctvg,
    unsigned* __restrict__ flags, float* __restrict__ out)
{
  extern __shared__ char smem[];
  unsigned short* Kl = (unsigned short*)smem;              // [512][64] skewed
  unsigned short* Vl = (unsigned short*)(smem + 65536);    // [512][64] skewed
  float* sc   = (float*)(smem + 131072);                   // [2][512]
  float* qx   = (float*)(smem + 135168);                   // [64]
  float* red  = (float*)(smem + 135424);                   // [32]
  float* mxs  = (float*)(smem + 135552);                   // [2]
  float* isl  = (float*)(smem + 135560);                   // [2]
  unsigned short* xint = (unsigned short*)(smem + 135680); // [16][160] bf16
  unsigned short* ht0  = (unsigned short*)(smem + 140800); // [16][128] bf16
  unsigned short* ht1  = (unsigned short*)(smem + 144896); // [16][128] bf16
  float* P = (float*)(smem + 148992);                      // [16][132] f32 (ctv, then ct)

  const int g = blockIdx.x;
  const int tid = threadIdx.x;
  const int b = g >> 1, half = g & 1;
  const int l = tid & 63, wv = tid >> 6;
  const int lr = l & 15, kg = l >> 4;
  const int col = wv * 16 + lr;
  const int rbase = kg * 4;
  unsigned* fQ = flags;            // 128 flags, stride 16 u32
  unsigned* fC = flags + 2048;     // 256 flags, stride 16 u32
  const unsigned* fQb = fQ + (size_t)b * 16;
  unsigned* fCg = fC + (size_t)g * 16;

  // one-time K/V load into LDS (row t: 8 16B octets, skew slot=(c+t)&7)
  {
    const int t = tid;
    const unsigned short* krow = kb + ((size_t)t * 128 + b) * 128 + half * 64;
    const unsigned short* vrow = vb + ((size_t)t * 128 + b) * 128 + half * 64;
#pragma unroll
    for (int c = 0; c < 8; ++c) {
      const s16x8 kv = *(const s16x8*)(krow + c * 8);
      const s16x8 vv = *(const s16x8*)(vrow + c * 8);
      const int sl = ((c + t) & 7) << 4;
      *(s16x8*)((char*)Kl + t * 128 + sl) = kv;
      *(s16x8*)((char*)Vl + t * 128 + sl) = vv;
    }
  }

  if (g < 8) {
    // ---- driver WG: both LSTM layers + q + Wo + lin for b in [g*16, g*16+16)
    const int b016 = g * 16;
    s16x8 wf0[4][5], wfh[4][4], wi1f[4][4], wh1f[4][4], wqf[4], wof[4];
    float b0v[4], b1v[4], c0r[4], c1r[4];
#pragma unroll
    for (int gi = 0; gi < 4; ++gi) {
#pragma unroll
      for (int kk = 0; kk < 5; ++kk)
        wf0[gi][kk] = *(const s16x8*)(W0p + (size_t)(gi * 128 + col) * 160 + kk * 32 + kg * 8);
#pragma unroll
      for (int kk = 0; kk < 4; ++kk) {
        wfh[gi][kk]  = *(const s16x8*)(Wh0 + (size_t)(gi * 128 + col) * 128 + kk * 32 + kg * 8);
        wi1f[gi][kk] = *(const s16x8*)(Wi1 + (size_t)(gi * 128 + col) * 128 + kk * 32 + kg * 8);
        wh1f[gi][kk] = *(const s16x8*)(Wh1 + (size_t)(gi * 128 + col) * 128 + kk * 32 + kg * 8);
      }
      b0v[gi] = b0[gi * 128 + col];
      b1v[gi] = b1[gi * 128 + col];
      c0r[gi] = 0.f; c1r[gi] = 0.f;
    }
#pragma unroll
    for (int kk = 0; kk < 4; ++kk) {
      wqf[kk] = *(const s16x8*)(Wqd + (size_t)col * 128 + kk * 32 + kg * 8);
      wof[kk] = *(const s16x8*)(Wod + (size_t)col * 128 + kk * 32 + kg * 8);
    }
    const float bqv_ = bq[col];
    const float bov_ = bo[col];
    for (int i = tid; i < 2560; i += 512) xint[i] = 0;
    for (int i = tid; i < 2048; i += 512) { ht0[i] = 0; ht1[i] = 0; }
    __syncthreads();

    for (int s = 0; s < 64; ++s) {
      // ---- layer 0: gates = W0.xin + Wh0.h0
      s16x8 ax[5], ah[4];
#pragma unroll
      for (int kk = 0; kk < 5; ++kk)
        ax[kk] = *(const s16x8*)((const char*)xint + lr * 320 + kk * 64 + kg * 16);
#pragma unroll
      for (int kk = 0; kk < 4; ++kk)
        ah[kk] = *(const s16x8*)((const char*)ht0 + lr * 256 + kk * 64 + kg * 16);
      f32x4 acc[4];
#pragma unroll
      for (int gi = 0; gi < 4; ++gi) acc[gi] = (f32x4){b0v[gi], b0v[gi], b0v[gi], b0v[gi]};
#pragma unroll
      for (int kk = 0; kk < 5; ++kk)
#pragma unroll
        for (int gi = 0; gi < 4; ++gi)
          acc[gi] = __builtin_amdgcn_mfma_f32_16x16x32_bf16(ax[kk], wf0[gi][kk], acc[gi], 0, 0, 0);
#pragma unroll
      for (int kk = 0; kk < 4; ++kk)
#pragma unroll
        for (int gi = 0; gi < 4; ++gi)
          acc[gi] = __builtin_amdgcn_mfma_f32_16x16x32_bf16(ah[kk], wfh[gi][kk], acc[gi], 0, 0, 0);
      __syncthreads();   // ht0 reads done
#pragma unroll
      for (int e = 0; e < 4; ++e) {
        const float gi_ = sigf(acc[0][e]), gf = sigf(acc[1][e]);
        const float gg = tanhf_(acc[2][e]), go = sigf(acc[3][e]);
        c0r[e] = gf * c0r[e] + gi_ * gg;
        ht0[(rbase + e) * 128 + col] = f2bf(go * tanhf_(c0r[e]));
      }
      __syncthreads();

      // ---- layer 1: gates = Wi1.h0 + Wh1.h1
      s16x8 ah0[4], ah1[4];
#pragma unroll
      for (int kk = 0; kk < 4; ++kk) {
        ah0[kk] = *(const s16x8*)((const char*)ht0 + lr * 256 + kk * 64 + kg * 16);
        ah1[kk] = *(const s16x8*)((const char*)ht1 + lr * 256 + kk * 64 + kg * 16);
      }
#pragma unroll
      for (int gi = 0; gi < 4; ++gi) acc[gi] = (f32x4){b1v[gi], b1v[gi], b1v[gi], b1v[gi]};
#pragma unroll
      for (int kk = 0; kk < 4; ++kk)
#pragma unroll
        for (int gi = 0; gi < 4; ++gi) {
          acc[gi] = __builtin_amdgcn_mfma_f32_16x16x32_bf16(ah0[kk], wi1f[gi][kk], acc[gi], 0, 0, 0);
          acc[gi] = __builtin_amdgcn_mfma_f32_16x16x32_bf16(ah1[kk], wh1f[gi][kk], acc[gi], 0, 0, 0);
        }
      __syncthreads();   // ht1 reads done
#pragma unroll
      for (int e = 0; e < 4; ++e) {
        const float gi_ = sigf(acc[0][e]), gf = sigf(acc[1][e]);
        const float gg = tanhf_(acc[2][e]), go = sigf(acc[3][e]);
        c1r[e] = gf * c1r[e] + gi_ * gg;
        ht1[(rbase + e) * 128 + col] = f2bf(go * tanhf_(c1r[e]));
      }
      __syncthreads();

      // ---- q = Wq.h1 + bq -> qg (f32, relaxed agent stores)
      s16x8 aq[4];
#pragma unroll
      for (int kk = 0; kk < 4; ++kk)
        aq[kk] = *(const s16x8*)((const char*)ht1 + lr * 256 + kk * 64 + kg * 16);
      f32x4 qa = (f32x4){bqv_, bqv_, bqv_, bqv_};
#pragma unroll
      for (int kk = 0; kk < 4; ++kk)
        qa = __builtin_amdgcn_mfma_f32_16x16x32_bf16(aq[kk], wqf[kk], qa, 0, 0, 0);
#pragma unroll
      for (int e = 0; e < 4; ++e)
        astoref(&qg[(size_t)(b016 + rbase + e) * 128 + col], qa[e]);
      __syncthreads();   // all waves' q stores drained (pre-barrier vmcnt)
      if (tid < 16) flag_set_fast(fQ + (size_t)(b016 + tid) * 16, (unsigned)(s + 1));

      // ---- own attention slice (overlaps other WGs' attention)
      attn_step(s, b, half, tid, l, wv, fQb, fCg, qg, ctvg, Kl, Vl, sc, qx, red, mxs, isl);

      // ---- wait for all 32 ctv producers of this batch group (no fence)
      if (tid < 32) {
        const unsigned* fp = fC + (size_t)(g * 32 + tid) * 16;
        while (__hip_atomic_load(fp, __ATOMIC_RELAXED, __HIP_MEMORY_SCOPE_AGENT) <= (unsigned)s) {}
      }
      __syncthreads();
      // gather ctv rows into P (row stride 132 f32 = 66 u64, kills bank conflicts)
      for (int i = tid; i < 1024; i += 512) {
        const int r = i >> 6, c2 = i & 63;
        ((unsigned long long*)P)[r * 66 + c2] =
            aload64((const unsigned long long*)ctvg + (size_t)b016 * 64 + i);
      }
      __syncthreads();
      // ---- ct = Wo.ctv + bo
      s16x8 act[4];
#pragma unroll
      for (int kk = 0; kk < 4; ++kk) {
        s16x8 r;
#pragma unroll
        for (int e = 0; e < 8; ++e) r[e] = (short)f2bf(P[lr * 132 + kk * 32 + kg * 8 + e]);
        act[kk] = r;
      }
      f32x4 acd = (f32x4){bov_, bov_, bov_, bov_};
#pragma unroll
      for (int kk = 0; kk < 4; ++kk)
        acd = __builtin_amdgcn_mfma_f32_16x16x32_bf16(act[kk], wof[kk], acd, 0, 0, 0);
      __syncthreads();   // P (ctv) reads done
#pragma unroll
      for (int e = 0; e < 4; ++e) {
        P[(rbase + e) * 132 + col] = acd[e];
        xint[(rbase + e) * 160 + 4 + col] = f2bf(acd[e]);
      }
      __syncthreads();
      // ---- y = [h1, ct] @ lin_W.T + lin_b : thread (bl, o, kc)
      {
        const int bl = tid >> 5, o = (tid >> 3) & 3, kc = tid & 7;
        const float* lw = linW + o * 256;
        float part = 0.f;
#pragma unroll
        for (int k2 = 0; k2 < 16; ++k2) {
          const int k = kc * 16 + k2;
          part += bf2f((short)ht1[bl * 128 + k]) * lw[k] + P[bl * 132 + k] * lw[128 + k];
        }
        part += __shfl_xor(part, 1);
        part += __shfl_xor(part, 2);
        part += __shfl_xor(part, 4);
        if (kc == 0) {
          const float yv = part + linb[o];
          out[((size_t)s * 128 + b016 + bl) * 4 + o] = yv;
          xint[bl * 160 + o] = f2bf(yv);
        }
      }
      __syncthreads();
    }
  } else {
    for (int s = 0; s < 64; ++s)
      attn_step(s, b, half, tid, l, wv, fQb, fCg, qg, ctvg, Kl, Vl, sc, qx, red, mxs, isl);
  }
}

// ---------------------------------------------------------------- launch
extern "C" void kernel_launch(void* const* d_in, const int* in_sizes, int n_in,
                              void* d_out, int out_size, void* d_ws, size_t ws_size,
                              hipStream_t stream) {
  (void)in_sizes; (void)n_in; (void)out_size; (void)ws_size;
  const float* x     = (const float*)d_in[0];
  const float* eWih0 = (const float*)d_in[1];
  const float* eWhh0 = (const float*)d_in[2];
  const float* eb0   = (const float*)d_in[3];
  const float* eWih1 = (const float*)d_in[4];
  const float* eWhh1 = (const float*)d_in[5];
  const float* eb1   = (const float*)d_in[6];
  const float* dWih0 = (const float*)d_in[7];
  const float* dWhh0 = (const float*)d_in[8];
  const float* db0   = (const float*)d_in[9];
  const float* dWih1 = (const float*)d_in[10];
  const float* dWhh1 = (const float*)d_in[11];
  const float* db1   = (const float*)d_in[12];
  const float* Wq    = (const float*)d_in[13];
  const float* bq    = (const float*)d_in[14];
  const float* Wk    = (const float*)d_in[15];
  const float* bk    = (const float*)d_in[16];
  const float* Wv    = (const float*)d_in[17];
  const float* bv    = (const float*)d_in[18];
  const float* Wo    = (const float*)d_in[19];
  const float* bo    = (const float*)d_in[20];
  const float* linW  = (const float*)d_in[21];
  const float* linb  = (const float*)d_in[22];

  char* w = (char*)d_ws;
  unsigned* flags = (unsigned*)w;                        // 32 KB flag region (64B-strided)
  float* qg   = (float*)(w + 65536);                     // 64 KB
  float* ctvg = (float*)(w + 131072);                    // 64 KB
  float* pre  = (float*)(w + 524288);                    // 128 MB
  size_t off = 524288 + (size_t)65536 * 512 * 4;
  unsigned short* hs0  = (unsigned short*)(w + off); off += (size_t)65536 * 128 * 2;
  unsigned short* enc  = (unsigned short*)(w + off); off += (size_t)65536 * 128 * 2;
  unsigned short* kbuf = (unsigned short*)(w + off); off += (size_t)65536 * 128 * 2;
  unsigned short* vbuf = (unsigned short*)(w + off); off += (size_t)65536 * 128 * 2;
  unsigned short* W0p  = (unsigned short*)(w + off); off += 512 * 160 * 2;
  unsigned short* Wh0d = (unsigned short*)(w + off); off += 512 * 128 * 2;
  unsigned short* Wi1d = (unsigned short*)(w + off); off += 512 * 128 * 2;
  unsigned short* Wh1d = (unsigned short*)(w + off); off += 512 * 128 * 2;
  unsigned short* Wqd  = (unsigned short*)(w + off); off += 128 * 128 * 2;
  unsigned short* Wod  = (unsigned short*)(w + off); off += 128 * 128 * 2;

  hipMemsetAsync(w, 0, 32768, stream);  // zero flags every call

  conv_pad<<<(512 * 160 + 255) / 256, 256, 0, stream>>>(dWih0, W0p, 512, 132, 160);
  conv_pad<<<(512 * 128 + 255) / 256, 256, 0, stream>>>(dWhh0, Wh0d, 512, 128, 128);
  conv_pad<<<(512 * 128 + 255) / 256, 256, 0, stream>>>(dWih1, Wi1d, 512, 128, 128);
  conv_pad<<<(512 * 128 + 255) / 256, 256, 0, stream>>>(dWhh1, Wh1d, 512, 128, 128);
  conv_pad<<<(128 * 128 + 255) / 256, 256, 0, stream>>>(Wq, Wqd, 128, 128, 128);
  conv_pad<<<(128 * 128 + 255) / 256, 256, 0, stream>>>(Wo, Wod, 128, 128, 128);

  // encoder
  gemm_bt<0, 0><<<dim3(4, 512), 256, 0, stream>>>((const void*)x, eWih0, eb0, (void*)pre, 65536, 512, 1024);
  lstm_scan<<<8, 512, 0, stream>>>(pre, eWhh0, hs0, 512);
  gemm_bt<1, 0><<<dim3(4, 512), 256, 0, stream>>>((const void*)hs0, eWih1, eb1, (void*)pre, 65536, 512, 128);
  lstm_scan<<<8, 512, 0, stream>>>(pre, eWhh1, enc, 512);
  // K/V projections
  gemm_bt<1, 1><<<dim3(1, 512), 256, 0, stream>>>((const void*)enc, Wk, bk, (void*)kbuf, 65536, 128, 128);
  gemm_bt<1, 1><<<dim3(1, 512), 256, 0, stream>>>((const void*)enc, Wv, bv, (void*)vbuf, 65536, 128, 128);

  // persistent decoder: 256 WGs = 1/CU, big dynamic LDS
  hipFuncSetAttribute((const void*)decoder_persist,
                      hipFuncAttributeMaxDynamicSharedMemorySize, DEC_SMEM);
  decoder_persist<<<256, 512, DEC_SMEM, stream>>>(kbuf, vbuf, W0p, Wh0d, Wi1d, Wh1d, Wqd, Wod,
      db0, db1, bq, bo, linW, linb, qg, ctvg, flags, (float*)d_out);
}

// Round 8
// 3968.187 us; speedup vs baseline: 3.2715x; 1.0040x over previous
//
#include <hip/hip_runtime.h>
#include <hip/hip_bf16.h>

typedef __attribute__((ext_vector_type(8))) short s16x8;
typedef __attribute__((ext_vector_type(4))) float f32x4;

__device__ inline unsigned short f2bf(float f) {
  unsigned u = __builtin_bit_cast(unsigned, f);
  unsigned r = (u + 0x7FFFu + ((u >> 16) & 1u)) >> 16;  // RTNE
  return (unsigned short)r;
}
__device__ inline float bf2f(short v) {
  return __builtin_bit_cast(float, ((unsigned)(unsigned short)v) << 16);
}
__device__ inline float bflo(unsigned w) {  // low bf16 of packed pair
  return __builtin_bit_cast(float, w << 16);
}
__device__ inline float bfhi(unsigned w) {  // high bf16 of packed pair
  return __builtin_bit_cast(float, w & 0xFFFF0000u);
}
__device__ inline float sigf(float x) { return 1.f / (1.f + __expf(-x)); }
__device__ inline float tanhf_(float x) { float e = __expf(2.f * x); return 1.f - 2.f / (e + 1.f); }

// ---------------------------------------------------------------- weight pack:
// src [rows][scols] f32 -> dst u32 [kkPairs][rows], dst[kk*rows+o] = pack(bf16(src[o][2kk]), bf16(src[o][2kk+1]))
__global__ void packT(const float* __restrict__ src, unsigned* __restrict__ dst,
                      int rows, int scols, int kkPairs) {
  int i = blockIdx.x * 256 + threadIdx.x;
  if (i >= kkPairs * rows) return;
  int kk = i / rows, o = i % rows;
  int k0 = 2 * kk, k1 = 2 * kk + 1;
  float lo = (k0 < scols) ? src[(size_t)o * scols + k0] : 0.f;
  float hi = (k1 < scols) ? src[(size_t)o * scols + k1] : 0.f;
  dst[i] = (unsigned)f2bf(lo) | ((unsigned)f2bf(hi) << 16);
}

// ---------------------------------------------------------------- GEMM C = A @ B^T + bias
#define BM 128
#define BN 128
#define BKK 32

template<int A_BF16, int C_BF16>
__global__ __launch_bounds__(256) void gemm_bt(const void* __restrict__ Av,
    const float* __restrict__ B, const float* __restrict__ bias,
    void* __restrict__ Cv, int M, int N, int K) {
  __shared__ short sA[BM * BKK];
  __shared__ short sB[BN * BKK];
  const int tid = threadIdx.x;
  const int l = tid & 63;
  const int wid = tid >> 6;
  const int wr = wid >> 1, wc = wid & 1;
  const int lr = l & 15, kg = l >> 4;
  const int bn = blockIdx.x, bm = blockIdx.y;
  const int arow = tid >> 1;
  const int acol = (tid & 1) * 16;

  f32x4 acc[4][4];
#pragma unroll
  for (int i = 0; i < 4; ++i)
#pragma unroll
    for (int j = 0; j < 4; ++j) acc[i][j] = (f32x4){0.f, 0.f, 0.f, 0.f};

  for (int kt = 0; kt < K; kt += BKK) {
    __syncthreads();
    if (A_BF16) {
      const unsigned short* src = (const unsigned short*)Av + (size_t)(bm * BM + arow) * K + kt + acol;
      *(s16x8*)&sA[arow * BKK + acol] = *(const s16x8*)src;
      *(s16x8*)&sA[arow * BKK + acol + 8] = *(const s16x8*)(src + 8);
    } else {
      const float* src = (const float*)Av + (size_t)(bm * BM + arow) * K + kt + acol;
      s16x8 v0, v1;
#pragma unroll
      for (int e = 0; e < 8; ++e) { v0[e] = (short)f2bf(src[e]); v1[e] = (short)f2bf(src[8 + e]); }
      *(s16x8*)&sA[arow * BKK + acol] = v0;
      *(s16x8*)&sA[arow * BKK + acol + 8] = v1;
    }
    {
      const float* src = B + (size_t)(bn * BN + arow) * K + kt + acol;
      s16x8 v0, v1;
#pragma unroll
      for (int e = 0; e < 8; ++e) { v0[e] = (short)f2bf(src[e]); v1[e] = (short)f2bf(src[8 + e]); }
      *(s16x8*)&sB[arow * BKK + acol] = v0;
      *(s16x8*)&sB[arow * BKK + acol + 8] = v1;
    }
    __syncthreads();
    s16x8 af[4], bfr[4];
#pragma unroll
    for (int mi = 0; mi < 4; ++mi)
      af[mi] = *(const s16x8*)&sA[(wr * 64 + mi * 16 + lr) * BKK + kg * 8];
#pragma unroll
    for (int ni = 0; ni < 4; ++ni)
      bfr[ni] = *(const s16x8*)&sB[(wc * 64 + ni * 16 + lr) * BKK + kg * 8];
#pragma unroll
    for (int mi = 0; mi < 4; ++mi)
#pragma unroll
      for (int ni = 0; ni < 4; ++ni)
        acc[mi][ni] = __builtin_amdgcn_mfma_f32_16x16x32_bf16(af[mi], bfr[ni], acc[mi][ni], 0, 0, 0);
  }
  const int r0 = bm * BM + wr * 64;
  const int c0 = bn * BN + wc * 64;
#pragma unroll
  for (int mi = 0; mi < 4; ++mi)
#pragma unroll
    for (int ni = 0; ni < 4; ++ni) {
      const int col = c0 + ni * 16 + lr;
      const float bv = bias[col];
#pragma unroll
      for (int e = 0; e < 4; ++e) {
        const int row = r0 + mi * 16 + kg * 4 + e;
        const float v = acc[mi][ni][e] + bv;
        if (C_BF16) ((unsigned short*)Cv)[(size_t)row * N + col] = f2bf(v);
        else        ((float*)Cv)[(size_t)row * N + col] = v;
      }
    }
}

// ---------------------------------------------------------------- encoder LSTM scan
__global__ __launch_bounds__(512) void lstm_scan(const float* __restrict__ pre,
    const float* __restrict__ Whh, unsigned short* __restrict__ hs, int T) {
  __shared__ unsigned short hb[2][2048];
  const int tid = threadIdx.x;
  const int l = tid & 63, w = tid >> 6;
  const int wg = blockIdx.x;
  const int lr = l & 15, kg = l >> 4;
  const int col = w * 16 + lr;
  const int rbase = kg * 4;

  s16x8 wf[4][4];
#pragma unroll
  for (int gi = 0; gi < 4; ++gi)
#pragma unroll
    for (int kk = 0; kk < 4; ++kk) {
      const float* p = Whh + (size_t)(gi * 128 + col) * 128 + kk * 32 + kg * 8;
#pragma unroll
      for (int e = 0; e < 8; ++e) wf[gi][kk][e] = (short)f2bf(p[e]);
    }
  for (int i = tid; i < 4096; i += 512) ((unsigned short*)hb)[i] = 0;
  float c[4] = {0.f, 0.f, 0.f, 0.f};

  const float* pbase = pre + ((size_t)(wg * 16 + rbase)) * 512 + col;
  float pf[16];
#pragma unroll
  for (int gi = 0; gi < 4; ++gi)
#pragma unroll
    for (int e = 0; e < 4; ++e) pf[gi * 4 + e] = pbase[e * 512 + gi * 128];
  __syncthreads();

  for (int t = 0; t < T; ++t) {
    const unsigned short* hc = hb[t & 1];
    unsigned short* hn = hb[(t & 1) ^ 1];
    s16x8 a[4];
#pragma unroll
    for (int kk = 0; kk < 4; ++kk) {
      const int byt = lr * 256 + ((kk * 64 + kg * 16) ^ ((lr & 7) << 4));
      a[kk] = *(const s16x8*)((const char*)hc + byt);
    }
    f32x4 acc[4];
#pragma unroll
    for (int gi = 0; gi < 4; ++gi)
      acc[gi] = (f32x4){pf[gi * 4], pf[gi * 4 + 1], pf[gi * 4 + 2], pf[gi * 4 + 3]};
    float pfn[16];
    if (t + 1 < T) {
      const float* pb2 = pbase + (size_t)(t + 1) * 65536;
#pragma unroll
      for (int gi = 0; gi < 4; ++gi)
#pragma unroll
        for (int e = 0; e < 4; ++e) pfn[gi * 4 + e] = pb2[e * 512 + gi * 128];
    } else {
#pragma unroll
      for (int i2 = 0; i2 < 16; ++i2) pfn[i2] = 0.f;
    }
#pragma unroll
    for (int kk = 0; kk < 4; ++kk)
#pragma unroll
      for (int gi = 0; gi < 4; ++gi)
        acc[gi] = __builtin_amdgcn_mfma_f32_16x16x32_bf16(a[kk], wf[gi][kk], acc[gi], 0, 0, 0);
#pragma unroll
    for (int e = 0; e < 4; ++e) {
      float gi_ = sigf(acc[0][e]);
      float gf  = sigf(acc[1][e]);
      float gg  = tanhf_(acc[2][e]);
      float go  = sigf(acc[3][e]);
      c[e] = gf * c[e] + gi_ * gg;
      float h = go * tanhf_(c[e]);
      unsigned short hu = f2bf(h);
      int row = rbase + e;
      int byt = row * 256 + ((col * 2) ^ ((row & 7) << 4));
      *(unsigned short*)((char*)hn + byt) = hu;
      hs[((size_t)t * 128 + wg * 16 + row) * 128 + col] = hu;
    }
#pragma unroll
    for (int i2 = 0; i2 < 16; ++i2) pf[i2] = pfn[i2];
    __syncthreads();
  }
}

// ---------------------------------------------------------------- self-contained decoder
// 128 WGs, one per batch, ZERO cross-WG communication.
// K in LDS (128 KB, staged once, 16-slot skew). V + all weights streamed from L2
// every step (transposed u32-packed bf16 pairs -> coalesced, L2-resident:
// per XCD 16 WGs x 128KB V + 0.6MB shared weights ~= 2.6MB < 4MB L2).
// All state (xin, h0,c0,h1,c1) f32 in LDS; weights bf16.

#define DEC_SMEM 149504

__global__ void __launch_bounds__(512, 1) decoder_single(
    const unsigned short* __restrict__ kb, const unsigned short* __restrict__ vb,
    const unsigned* __restrict__ w0t,  const unsigned* __restrict__ wh0t,
    const unsigned* __restrict__ wi1t, const unsigned* __restrict__ wh1t,
    const unsigned* __restrict__ wqt,  const unsigned* __restrict__ wot,
    const float* __restrict__ b0, const float* __restrict__ b1,
    const float* __restrict__ bq, const float* __restrict__ bo,
    const float* __restrict__ linW, const float* __restrict__ linb,
    float* __restrict__ out)
{
  extern __shared__ char smem[];
  unsigned short* Kl = (unsigned short*)smem;      // [512 rows][16 slots x 16B] skewed (131072 B)
  float* xin = (float*)(smem + 131072);            // [136] f32 (y[4], ct[128], pad)
  float* h0  = (float*)(smem + 131648);            // [128]
  float* h1  = (float*)(smem + 132160);            // [128]
  float* c0  = (float*)(smem + 132672);            // [128]
  float* c1  = (float*)(smem + 133184);            // [128]
  float* gb  = (float*)(smem + 133696);            // [512] gates, reused as ctv[128]
  float* qx  = (float*)(smem + 135744);            // [128]
  float* sc  = (float*)(smem + 136256);            // [4][512] exp-scores
  float* avp = (float*)(smem + 144448);            // [4][128] AV partials
  float* part= (float*)(smem + 146496);            // [4][128] matvec partials (q / Wo)
  float* red = (float*)(smem + 148544);            // [64]
  float* mxs = (float*)(smem + 148800);            // [4]
  float* isl = (float*)(smem + 148816);            // [4]

  const int b = blockIdx.x;
  const int tid = threadIdx.x;
  const int l = tid & 63, wv = tid >> 6;

  // ---- one-time K staging (coalesced read, skewed write: slot' = (slot+t)&15)
  {
    const unsigned* kb32 = (const unsigned*)kb;
    for (int it = 0; it < 64; ++it) {
      const int i = tid + it * 512;                // i = t*64 + c32
      const int t = i >> 6, c32 = i & 63;
      const unsigned v = kb32[(size_t)t * 8192 + b * 64 + c32];
      const int slot = c32 >> 2, w32 = c32 & 3;
      *(unsigned*)((char*)Kl + t * 256 + (((slot + t) & 15) << 4) + w32 * 4) = v;
    }
  }
  // ---- state init
  if (tid < 136) xin[tid] = 0.f;
  if (tid < 128) { h0[tid] = 0.f; h1[tid] = 0.f; c0[tid] = 0.f; c1[tid] = 0.f; }
  const float b0r = b0[tid];
  const float b1r = b1[tid];
  __syncthreads();

  for (int s = 0; s < 64; ++s) {
    // ======== LSTM layer 0: gb[o] = b0 + W0.xin + Wh0.h0  (thread o = tid)
    {
      float acc = b0r;
      const unsigned* wp = w0t + tid;
#pragma unroll 8
      for (int kk = 0; kk < 68; ++kk) {
        const unsigned w2 = wp[kk * 512];
        const float2 x2 = *(const float2*)(xin + 2 * kk);
        acc += x2.x * bflo(w2) + x2.y * bfhi(w2);
      }
      const unsigned* hp = wh0t + tid;
#pragma unroll 8
      for (int kk = 0; kk < 64; ++kk) {
        const unsigned w2 = hp[kk * 512];
        const float2 h2 = *(const float2*)(h0 + 2 * kk);
        acc += h2.x * bflo(w2) + h2.y * bfhi(w2);
      }
      gb[tid] = acc;
    }
    __syncthreads();
    if (tid < 128) {
      const float ig = sigf(gb[tid]), fg = sigf(gb[128 + tid]);
      const float gg = tanhf_(gb[256 + tid]), og = sigf(gb[384 + tid]);
      const float c = fg * c0[tid] + ig * gg;
      c0[tid] = c;
      h0[tid] = og * tanhf_(c);
    }
    __syncthreads();
    // ======== LSTM layer 1: gb[o] = b1 + Wi1.h0 + Wh1.h1
    {
      float acc = b1r;
      const unsigned* wp = wi1t + tid;
      const unsigned* hp = wh1t + tid;
#pragma unroll 8
      for (int kk = 0; kk < 64; ++kk) {
        const unsigned wa = wp[kk * 512];
        const unsigned wb = hp[kk * 512];
        const float2 a2 = *(const float2*)(h0 + 2 * kk);
        const float2 b2 = *(const float2*)(h1 + 2 * kk);
        acc += a2.x * bflo(wa) + a2.y * bfhi(wa) + b2.x * bflo(wb) + b2.y * bfhi(wb);
      }
      gb[tid] = acc;
    }
    __syncthreads();
    if (tid < 128) {
      const float ig = sigf(gb[tid]), fg = sigf(gb[128 + tid]);
      const float gg = tanhf_(gb[256 + tid]), og = sigf(gb[384 + tid]);
      const float c = fg * c1[tid] + ig * gg;
      c1[tid] = c;
      h1[tid] = og * tanhf_(c);
    }
    __syncthreads();
    // ======== q = Wq.h1 + bq  (quarter-split: o=tid&127, qd=tid>>7)
    {
      const int o = tid & 127, qd = tid >> 7;
      float acc = 0.f;
      const unsigned* wp = wqt + o;
#pragma unroll
      for (int kk = qd * 16; kk < qd * 16 + 16; ++kk) {
        const unsigned w2 = wp[kk * 128];
        const float2 h2 = *(const float2*)(h1 + 2 * kk);
        acc += h2.x * bflo(w2) + h2.y * bfhi(w2);
      }
      part[qd * 128 + o] = acc;
    }
    __syncthreads();
    if (tid < 128)
      qx[tid] = bq[tid] + part[tid] + part[128 + tid] + part[256 + tid] + part[384 + tid];
    __syncthreads();
    // ======== scores: thread t = tid handles K row t, 4 heads
    float s4[4];
    {
      const int t = tid;
      s4[0] = 0.f; s4[1] = 0.f; s4[2] = 0.f; s4[3] = 0.f;
      const char* krow = (const char*)Kl + t * 256;
#pragma unroll
      for (int c = 0; c < 16; ++c) {
        const s16x8 kv = *(const s16x8*)(krow + (((c + t) & 15) << 4));
        const float* qp = qx + c * 8;
        float d = 0.f;
#pragma unroll
        for (int e = 0; e < 8; ++e) d += qp[e] * bf2f(kv[e]);
        s4[c >> 2] += d;
      }
      const float scale = 0.1767766952966369f;  // 1/sqrt(32)
#pragma unroll
      for (int h = 0; h < 4; ++h) {
        s4[h] *= scale;
        float m = s4[h];
#pragma unroll
        for (int off = 32; off > 0; off >>= 1) m = fmaxf(m, __shfl_xor(m, off));
        if (l == 0) red[h * 8 + wv] = m;
      }
    }
    __syncthreads();
    if (tid < 4) {
      float m = red[tid * 8];
#pragma unroll
      for (int w2 = 1; w2 < 8; ++w2) m = fmaxf(m, red[tid * 8 + w2]);
      mxs[tid] = m;
    }
    __syncthreads();
#pragma unroll
    for (int h = 0; h < 4; ++h) {
      float p = __expf(s4[h] - mxs[h]);
      sc[h * 512 + tid] = p;
#pragma unroll
      for (int off = 32; off > 0; off >>= 1) p += __shfl_xor(p, off);
      if (l == 0) red[32 + h * 8 + wv] = p;
    }
    __syncthreads();
    if (tid < 4) {
      float sm = red[32 + tid * 8];
#pragma unroll
      for (int w2 = 1; w2 < 8; ++w2) sm += red[32 + tid * 8 + w2];
      isl[tid] = 1.f / sm;
    }
    __syncthreads();
    // ======== AV: thread (tc=tid>>7, d=tid&127); V streamed from L2, lane-contiguous
    {
      const int d = tid & 127, tc = tid >> 7, h = d >> 5;
      const unsigned short* vp = vb + (size_t)(tc * 128) * 16384 + b * 128 + d;
      const float* scp = sc + h * 512 + tc * 128;
      float acc = 0.f;
#pragma unroll 8
      for (int tt = 0; tt < 128; ++tt)
        acc += scp[tt] * bf2f((short)vp[(size_t)tt * 16384]);
      avp[tc * 128 + d] = acc;
    }
    __syncthreads();
    if (tid < 128)
      gb[tid] = (avp[tid] + avp[128 + tid] + avp[256 + tid] + avp[384 + tid]) * isl[tid >> 5];
    __syncthreads();
    // ======== ct = Wo.ctv + bo (quarter-split), write into xin[4..131]
    {
      const int o = tid & 127, qd = tid >> 7;
      float acc = 0.f;
      const unsigned* wp = wot + o;
#pragma unroll
      for (int kk = qd * 16; kk < qd * 16 + 16; ++kk) {
        const unsigned w2 = wp[kk * 128];
        const float2 c2 = *(const float2*)(gb + 2 * kk);
        acc += c2.x * bflo(w2) + c2.y * bfhi(w2);
      }
      part[qd * 128 + o] = acc;
    }
    __syncthreads();
    if (tid < 128)
      xin[4 + tid] = bo[tid] + part[tid] + part[128 + tid] + part[256 + tid] + part[384 + tid];
    __syncthreads();
    // ======== y = [h1, ct] @ lin_W.T + lin_b : threads<256, (o=tid>>6, j=tid&63)
    if (tid < 256) {
      const int o = tid >> 6, j = tid & 63;
      const float* lw = linW + o * 256;
      float p = h1[j] * lw[j] + h1[j + 64] * lw[j + 64]
              + xin[4 + j] * lw[128 + j] + xin[4 + j + 64] * lw[192 + j];
#pragma unroll
      for (int off = 32; off > 0; off >>= 1) p += __shfl_xor(p, off);
      if (j == 0) {
        const float yv = p + linb[o];
        out[((size_t)s * 128 + b) * 4 + o] = yv;
        xin[o] = yv;
      }
    }
    __syncthreads();
  }
}

// ---------------------------------------------------------------- launch
extern "C" void kernel_launch(void* const* d_in, const int* in_sizes, int n_in,
                              void* d_out, int out_size, void* d_ws, size_t ws_size,
                              hipStream_t stream) {
  (void)in_sizes; (void)n_in; (void)out_size; (void)ws_size;
  const float* x     = (const float*)d_in[0];
  const float* eWih0 = (const float*)d_in[1];
  const float* eWhh0 = (const float*)d_in[2];
  const float* eb0   = (const float*)d_in[3];
  const float* eWih1 = (const float*)d_in[4];
  const float* eWhh1 = (const float*)d_in[5];
  const float* eb1   = (const float*)d_in[6];
  const float* dWih0 = (const float*)d_in[7];
  const float* dWhh0 = (const float*)d_in[8];
  const float* db0   = (const float*)d_in[9];
  const float* dWih1 = (const float*)d_in[10];
  const float* dWhh1 = (const float*)d_in[11];
  const float* db1   = (const float*)d_in[12];
  const float* Wq    = (const float*)d_in[13];
  const float* bq    = (const float*)d_in[14];
  const float* Wk    = (const float*)d_in[15];
  const float* bk    = (const float*)d_in[16];
  const float* Wv    = (const float*)d_in[17];
  const float* bv    = (const float*)d_in[18];
  const float* Wo    = (const float*)d_in[19];
  const float* bo    = (const float*)d_in[20];
  const float* linW  = (const float*)d_in[21];
  const float* linb  = (const float*)d_in[22];

  char* w = (char*)d_ws;
  float* pre  = (float*)(w + 524288);                    // 128 MB
  size_t off = 524288 + (size_t)65536 * 512 * 4;
  unsigned short* hs0  = (unsigned short*)(w + off); off += (size_t)65536 * 128 * 2;
  unsigned short* enc  = (unsigned short*)(w + off); off += (size_t)65536 * 128 * 2;
  unsigned short* kbuf = (unsigned short*)(w + off); off += (size_t)65536 * 128 * 2;
  unsigned short* vbuf = (unsigned short*)(w + off); off += (size_t)65536 * 128 * 2;
  unsigned* w0t  = (unsigned*)(w + off); off += (size_t)68 * 512 * 4;
  unsigned* wh0t = (unsigned*)(w + off); off += (size_t)64 * 512 * 4;
  unsigned* wi1t = (unsigned*)(w + off); off += (size_t)64 * 512 * 4;
  unsigned* wh1t = (unsigned*)(w + off); off += (size_t)64 * 512 * 4;
  unsigned* wqt  = (unsigned*)(w + off); off += (size_t)64 * 128 * 4;
  unsigned* wot  = (unsigned*)(w + off); off += (size_t)64 * 128 * 4;

  // decoder weight packing (transposed, bf16-pair u32)
  packT<<<(68 * 512 + 255) / 256, 256, 0, stream>>>(dWih0, w0t, 512, 132, 68);
  packT<<<(64 * 512 + 255) / 256, 256, 0, stream>>>(dWhh0, wh0t, 512, 128, 64);
  packT<<<(64 * 512 + 255) / 256, 256, 0, stream>>>(dWih1, wi1t, 512, 128, 64);
  packT<<<(64 * 512 + 255) / 256, 256, 0, stream>>>(dWhh1, wh1t, 512, 128, 64);
  packT<<<(64 * 128 + 255) / 256, 256, 0, stream>>>(Wq, wqt, 128, 128, 64);
  packT<<<(64 * 128 + 255) / 256, 256, 0, stream>>>(Wo, wot, 128, 128, 64);

  // encoder
  gemm_bt<0, 0><<<dim3(4, 512), 256, 0, stream>>>((const void*)x, eWih0, eb0, (void*)pre, 65536, 512, 1024);
  lstm_scan<<<8, 512, 0, stream>>>(pre, eWhh0, hs0, 512);
  gemm_bt<1, 0><<<dim3(4, 512), 256, 0, stream>>>((const void*)hs0, eWih1, eb1, (void*)pre, 65536, 512, 128);
  lstm_scan<<<8, 512, 0, stream>>>(pre, eWhh1, enc, 512);
  // K/V projections
  gemm_bt<1, 1><<<dim3(1, 512), 256, 0, stream>>>((const void*)enc, Wk, bk, (void*)kbuf, 65536, 128, 128);
  gemm_bt<1, 1><<<dim3(1, 512), 256, 0, stream>>>((const void*)enc, Wv, bv, (void*)vbuf, 65536, 128, 128);

  // self-contained decoder: 128 WGs, one per batch, no cross-WG sync
  hipFuncSetAttribute((const void*)decoder_single,
                      hipFuncAttributeMaxDynamicSharedMemorySize, DEC_SMEM);
  decoder_single<<<128, 512, DEC_SMEM, stream>>>(kbuf, vbuf, w0t, wh0t, wi1t, wh1t, wqt, wot,
      db0, db1, bq, bo, linW, linb, (float*)d_out);
}